// Round 7
// baseline (1544.011 us; speedup 1.0000x reference)
//
#include <hip/hip_runtime.h>
#include <math.h>

#define F_IN 256
#define HC   256   // H*C
#define H_   4
#define C_   64
#define KTOP 10
#define NEG_SLOPE 0.2f

// ================= GEMM: C[M,No] = A[M,K] @ B[No,K]^T (fp32) =================
#define BM 128
#define BN 128
#define BK 16
#define LDP (BM + 4)
__global__ __launch_bounds__(256) void gemm_nt(const float* __restrict__ A,
                                               const float* __restrict__ B,
                                               float* __restrict__ Cc,
                                               int M, int K, int No) {
  __shared__ float As[BK][LDP];
  __shared__ float Bs[BK][LDP];
  const int bm = blockIdx.x * BM;
  const int bn = blockIdx.y * BN;
  const int tid = threadIdx.x;
  const int tx = tid & 15, ty = tid >> 4;
  const int lrow = tid >> 1;
  const int lk   = (tid & 1) << 3;
  const bool arow_ok = (bm + lrow < M);
  const float* aptr = A + (size_t)(bm + lrow) * K + lk;
  const float* bptr = B + (size_t)(bn + lrow) * K + lk;
  float acc[8][8] = {};
  for (int k0 = 0; k0 < K; k0 += BK) {
    float4 a0 = make_float4(0.f, 0.f, 0.f, 0.f), a1 = a0;
    if (arow_ok) {
      const float* ap = aptr + k0;
      a0 = *(const float4*)ap;
      a1 = *(const float4*)(ap + 4);
    }
    const float* bp = bptr + k0;
    float4 b0 = *(const float4*)bp;
    float4 b1 = *(const float4*)(bp + 4);
    __syncthreads();
    As[lk + 0][lrow] = a0.x; As[lk + 1][lrow] = a0.y; As[lk + 2][lrow] = a0.z; As[lk + 3][lrow] = a0.w;
    As[lk + 4][lrow] = a1.x; As[lk + 5][lrow] = a1.y; As[lk + 6][lrow] = a1.z; As[lk + 7][lrow] = a1.w;
    Bs[lk + 0][lrow] = b0.x; Bs[lk + 1][lrow] = b0.y; Bs[lk + 2][lrow] = b0.z; Bs[lk + 3][lrow] = b0.w;
    Bs[lk + 4][lrow] = b1.x; Bs[lk + 5][lrow] = b1.y; Bs[lk + 6][lrow] = b1.z; Bs[lk + 7][lrow] = b1.w;
    __syncthreads();
#pragma unroll
    for (int kk = 0; kk < BK; ++kk) {
      float a[8];
      *(float4*)&a[0] = *(const float4*)&As[kk][ty * 8];
      *(float4*)&a[4] = *(const float4*)&As[kk][ty * 8 + 4];
      {
        float4 bv = *(const float4*)&Bs[kk][tx * 4];
#pragma unroll
        for (int i = 0; i < 8; ++i) {
          acc[i][0] += a[i] * bv.x; acc[i][1] += a[i] * bv.y;
          acc[i][2] += a[i] * bv.z; acc[i][3] += a[i] * bv.w;
        }
      }
      {
        float4 bv = *(const float4*)&Bs[kk][64 + tx * 4];
#pragma unroll
        for (int i = 0; i < 8; ++i) {
          acc[i][4] += a[i] * bv.x; acc[i][5] += a[i] * bv.y;
          acc[i][6] += a[i] * bv.z; acc[i][7] += a[i] * bv.w;
        }
      }
    }
  }
#pragma unroll
  for (int i = 0; i < 8; ++i) {
    int r = bm + ty * 8 + i;
    if (r < M) {
      float* cp = Cc + (size_t)r * No + bn;
      *(float4*)(cp + tx * 4) = make_float4(acc[i][0], acc[i][1], acc[i][2], acc[i][3]);
      *(float4*)(cp + 64 + tx * 4) = make_float4(acc[i][4], acc[i][5], acc[i][6], acc[i][7]);
    }
  }
}

// ============ MLP layer 1: hid = relu(A @ B^T + bias), same tiling ============
__global__ __launch_bounds__(256) void gemm_bias_relu(const float* __restrict__ A,
                                                      const float* __restrict__ B,
                                                      const float* __restrict__ bias,
                                                      float* __restrict__ Cc,
                                                      int M, int K, int No) {
  __shared__ float As[BK][LDP];
  __shared__ float Bs[BK][LDP];
  const int bm = blockIdx.x * BM;
  const int bn = blockIdx.y * BN;
  const int tid = threadIdx.x;
  const int tx = tid & 15, ty = tid >> 4;
  const int lrow = tid >> 1;
  const int lk   = (tid & 1) << 3;
  const bool arow_ok = (bm + lrow < M);
  const bool brow_ok = (bn + lrow < No);
  const float* aptr = A + (size_t)(bm + lrow) * K + lk;
  const float* bptr = B + (size_t)(bn + lrow) * K + lk;
  float acc[8][8] = {};
  for (int k0 = 0; k0 < K; k0 += BK) {
    float4 a0 = make_float4(0.f, 0.f, 0.f, 0.f), a1 = a0, b0 = a0, b1 = a0;
    if (arow_ok) {
      const float* ap = aptr + k0;
      a0 = *(const float4*)ap;
      a1 = *(const float4*)(ap + 4);
    }
    if (brow_ok) {
      const float* bp = bptr + k0;
      b0 = *(const float4*)bp;
      b1 = *(const float4*)(bp + 4);
    }
    __syncthreads();
    As[lk + 0][lrow] = a0.x; As[lk + 1][lrow] = a0.y; As[lk + 2][lrow] = a0.z; As[lk + 3][lrow] = a0.w;
    As[lk + 4][lrow] = a1.x; As[lk + 5][lrow] = a1.y; As[lk + 6][lrow] = a1.z; As[lk + 7][lrow] = a1.w;
    Bs[lk + 0][lrow] = b0.x; Bs[lk + 1][lrow] = b0.y; Bs[lk + 2][lrow] = b0.z; Bs[lk + 3][lrow] = b0.w;
    Bs[lk + 4][lrow] = b1.x; Bs[lk + 5][lrow] = b1.y; Bs[lk + 6][lrow] = b1.z; Bs[lk + 7][lrow] = b1.w;
    __syncthreads();
#pragma unroll
    for (int kk = 0; kk < BK; ++kk) {
      float a[8];
      *(float4*)&a[0] = *(const float4*)&As[kk][ty * 8];
      *(float4*)&a[4] = *(const float4*)&As[kk][ty * 8 + 4];
      {
        float4 bv = *(const float4*)&Bs[kk][tx * 4];
#pragma unroll
        for (int i = 0; i < 8; ++i) {
          acc[i][0] += a[i] * bv.x; acc[i][1] += a[i] * bv.y;
          acc[i][2] += a[i] * bv.z; acc[i][3] += a[i] * bv.w;
        }
      }
      {
        float4 bv = *(const float4*)&Bs[kk][64 + tx * 4];
#pragma unroll
        for (int i = 0; i < 8; ++i) {
          acc[i][4] += a[i] * bv.x; acc[i][5] += a[i] * bv.y;
          acc[i][6] += a[i] * bv.z; acc[i][7] += a[i] * bv.w;
        }
      }
    }
  }
#pragma unroll
  for (int i = 0; i < 8; ++i) {
    int r = bm + ty * 8 + i;
    if (r < M) {
      float* cp = Cc + (size_t)r * No + bn;
#pragma unroll
      for (int j = 0; j < 4; ++j) {
        int col = tx * 4 + j;
        cp[col] = fmaxf(acc[i][j] + bias[bn + col], 0.f);
      }
#pragma unroll
      for (int j = 0; j < 4; ++j) {
        int col = 64 + tx * 4 + j;
        cp[col] = fmaxf(acc[i][4 + j] + bias[bn + col], 0.f);
      }
    }
  }
}

// ============ MLP layer 2: out[n,o] = <hid[n,:], Wl2[o,:]> + bl2[o] ============
__global__ __launch_bounds__(256) void head_out(const float* __restrict__ hid,
                                                const float* __restrict__ Wl2,
                                                const float* __restrict__ bl2,
                                                float* __restrict__ out, int n_nodes) {
  int t = blockIdx.x * 256 + threadIdx.x;
  int n = t >> 4, o = t & 15;
  if (n >= n_nodes) return;
  const float4* hp = (const float4*)(hid + (size_t)n * 128);
  const float4* wp = (const float4*)(Wl2 + (size_t)o * 128);
  float acc = bl2[o];
#pragma unroll
  for (int k = 0; k < 32; ++k) {
    float4 hv = hp[k], wv = wp[k];
    acc += hv.x * wv.x + hv.y * wv.y + hv.z * wv.z + hv.w * wv.w;
  }
  out[(size_t)n * 16 + o] = acc;
}

// =========== exact (fp64) attention-score folds, both convs ===========
__global__ __launch_bounds__(256) void fold_att1(const float* __restrict__ W1,
                                                 const float* __restrict__ att_s,
                                                 const float* __restrict__ att_d,
                                                 double* __restrict__ wt) {
  int t = blockIdx.x * 256 + threadIdx.x;   // t = h*HC + k, total 1024
  if (t >= H_ * HC) return;
  int h = t >> 8;
  int k = t & (HC - 1);
  double s = 0.0, d = 0.0;
#pragma unroll 4
  for (int c = 0; c < C_; ++c) {
    double w = (double)W1[(size_t)(h * C_ + c) * HC + k];
    s += w * (double)att_s[h * C_ + c];
    d += w * (double)att_d[h * C_ + c];
  }
  wt[(size_t)(2 * h + 0) * HC + k] = s;
  wt[(size_t)(2 * h + 1) * HC + k] = d;
}

__global__ __launch_bounds__(256) void fold_att2(const float* __restrict__ W2,
                                                 const float* __restrict__ att_s,
                                                 const float* __restrict__ att_d,
                                                 double* __restrict__ u_s,
                                                 double* __restrict__ u_d) {
  int t = blockIdx.x * 256 + threadIdx.x;
  if (t >= H_ * HC) return;
  int h = t >> 8;
  int k = t & (HC - 1);
  double s = 0.0, d = 0.0;
#pragma unroll 4
  for (int c = 0; c < C_; ++c) {
    double w = (double)W2[(size_t)(h * C_ + c) * HC + k];
    s += w * (double)att_s[h * C_ + c];
    d += w * (double)att_d[h * C_ + c];
  }
  u_s[t] = s;
  u_d[t] = d;
}

// vv -> wt rows 8..39, plus cst[8] (cst[0..3]=s, cst[4..7]=d)
__global__ __launch_bounds__(256) void fold_vv(const float* __restrict__ W1,
                                               const double* __restrict__ u2s,
                                               const double* __restrict__ u2d,
                                               const float* __restrict__ b1,
                                               double* __restrict__ wt,
                                               double* __restrict__ cst) {
  int t = blockIdx.x * 256 + threadIdx.x;
  if (t < 8192) {
    int type = t >> 12;          // 0=s, 1=d
    int rem = t & 4095;          // hh*256 + j
    int j = rem & 255;
    int hh = rem >> 8;           // h*4 + h'
    int h = hh >> 2, hp = hh & 3;
    const double* u2 = type ? u2d : u2s;
    double acc = 0.0;
#pragma unroll 4
    for (int c = 0; c < C_; ++c)
      acc += (double)W1[(size_t)(h * C_ + c) * HC + j] * u2[hp * HC + h * C_ + c];
    wt[(size_t)(8 + type * 16 + hh) * HC + j] = acc;
  } else if (t < 8200) {
    int q = t - 8192;            // 0..7
    const double* u2 = (q >> 2) ? u2d : u2s;
    int hp = q & 3;
    double acc = 0.0;
    for (int k = 0; k < HC; ++k) acc += (double)b1[k] * u2[hp * HC + k];
    cst[q] = acc;
  }
}

// ====== score GEMM — C[N,40] = x[N,256] . wt[40,256]^T, fp64 acc ======
#define SNB 128
#define SKB 32
__global__ __launch_bounds__(256) void scores_gemm(const float* __restrict__ x,
                                                   const double* __restrict__ wt,
                                                   double* __restrict__ as1,
                                                   double* __restrict__ ad1,
                                                   double* __restrict__ zz, int n_nodes) {
  __shared__ float  Xs[SNB][SKB + 1];
  __shared__ double Ws[40][SKB + 1];
  const int tid = threadIdx.x;
  const int n0 = blockIdx.x * SNB;
  const int g = tid & 3;
  const int p = tid >> 2;
  double acc0[10] = {}, acc1[10] = {};
  for (int k0 = 0; k0 < HC; k0 += SKB) {
    __syncthreads();
    {
      int row = tid >> 1;
      int colb = (tid & 1) * 16;
      float* d = &Xs[row][colb];
      int n = n0 + row;
      if (n < n_nodes) {
        const float* xp = x + (size_t)n * HC + k0 + colb;
        float4 v0 = *(const float4*)(xp);
        float4 v1 = *(const float4*)(xp + 4);
        float4 v2 = *(const float4*)(xp + 8);
        float4 v3 = *(const float4*)(xp + 12);
        d[0] = v0.x;  d[1] = v0.y;  d[2] = v0.z;  d[3] = v0.w;
        d[4] = v1.x;  d[5] = v1.y;  d[6] = v1.z;  d[7] = v1.w;
        d[8] = v2.x;  d[9] = v2.y;  d[10] = v2.z; d[11] = v2.w;
        d[12] = v3.x; d[13] = v3.y; d[14] = v3.z; d[15] = v3.w;
      } else {
#pragma unroll
        for (int j = 0; j < 16; ++j) d[j] = 0.f;
      }
    }
#pragma unroll
    for (int q = 0; q < 5; ++q) {
      int idx = tid + q * 256;
      int row = idx >> 5, col = idx & 31;
      Ws[row][col] = wt[(size_t)row * HC + k0 + col];
    }
    __syncthreads();
#pragma unroll
    for (int kk = 0; kk < SKB; ++kk) {
      double xv0 = (double)Xs[2 * p][kk];
      double xv1 = (double)Xs[2 * p + 1][kk];
#pragma unroll
      for (int ci = 0; ci < 10; ++ci) {
        double w = Ws[g * 10 + ci][kk];
        acc0[ci] += xv0 * w;
        acc1[ci] += xv1 * w;
      }
    }
  }
  const int na = n0 + 2 * p;
  const int nb = na + 1;
  if (na < n_nodes) {
#pragma unroll
    for (int ci = 0; ci < 10; ++ci) {
      int c = g * 10 + ci;
      double v = acc0[ci];
      if (c < 8)       ((c & 1) ? ad1 : as1)[na * H_ + (c >> 1)] = v;
      else if (c < 24) { int hh = c - 8;  zz[((size_t)na * H_ + (hh >> 2)) * 8 + (hh & 3)] = v; }
      else             { int hh = c - 24; zz[((size_t)na * H_ + (hh >> 2)) * 8 + 4 + (hh & 3)] = v; }
    }
  }
  if (nb < n_nodes) {
#pragma unroll
    for (int ci = 0; ci < 10; ++ci) {
      int c = g * 10 + ci;
      double v = acc1[ci];
      if (c < 8)       ((c & 1) ? ad1 : as1)[nb * H_ + (c >> 1)] = v;
      else if (c < 24) { int hh = c - 8;  zz[((size_t)nb * H_ + (hh >> 2)) * 8 + (hh & 3)] = v; }
      else             { int hh = c - 24; zz[((size_t)nb * H_ + (hh >> 2)) * 8 + 4 + (hh & 3)] = v; }
    }
  }
}

// ====================== CSR build + degree binning ======================
__global__ void count_edges(const int* __restrict__ dst, int E_, int* __restrict__ counts) {
  int e = blockIdx.x * blockDim.x + threadIdx.x;
  if (e < E_) atomicAdd(&counts[dst[e]], 1);
}

#define SCAN_T 1024
__global__ __launch_bounds__(SCAN_T) void scan_offsets(const int* __restrict__ counts,
                                                       int n_nodes, int* __restrict__ row_start,
                                                       int* __restrict__ wptr, int E_) {
  __shared__ int part[SCAN_T];
  int t = threadIdx.x;
  int chunk = (n_nodes + SCAN_T - 1) / SCAN_T;
  int lo = t * chunk;
  int hi = lo + chunk; if (hi > n_nodes) hi = n_nodes;
  int s = 0;
  for (int i = lo; i < hi; ++i) s += counts[i];
  part[t] = s;
  __syncthreads();
  for (int off = 1; off < SCAN_T; off <<= 1) {
    int v = (t >= off) ? part[t - off] : 0;
    __syncthreads();
    part[t] += v;
    __syncthreads();
  }
  int run = part[t] - s;
  for (int i = lo; i < hi; ++i) {
    int c = counts[i];
    row_start[i] = run;
    wptr[i] = run;
    run += c;
  }
  if (t == SCAN_T - 1) row_start[n_nodes] = E_;
}

__global__ void scatter_edges(const int* __restrict__ src, const int* __restrict__ dst, int E_,
                              int* __restrict__ wptr, int* __restrict__ csr_src) {
  int e = blockIdx.x * blockDim.x + threadIdx.x;
  if (e < E_) {
    int p = atomicAdd(&wptr[dst[e]], 1);
    csr_src[p] = src[e];
  }
}

// bin nodes by degree: class 0 = deg<=32 (32-lane-group select), class 1 = deg>32
__global__ void bin_nodes(const int* __restrict__ row_start, int n_nodes,
                          int* __restrict__ list32, int* __restrict__ list64,
                          int* __restrict__ cnt) {
  int n = blockIdx.x * blockDim.x + threadIdx.x;
  if (n >= n_nodes) return;
  int deg = row_start[n + 1] - row_start[n];
  if (deg <= 32) { int p = atomicAdd(&cnt[0], 1); list32[p] = n; }
  else           { int p = atomicAdd(&cnt[1], 1); list64[p] = n; }
}

// ====================== top-K select (degree-binned) ======================
// R18: deg<=32 nodes run a 32-lane-group bitonic -> 2 (node,head) items per
// wave instruction (was 1 per 64-lane wave with ~75% idle lanes at deg~16).
// Direction bits use group-relative slot; payload lane ids stay absolute so
// __shfl pulls work. Same fp64 comparator (v desc, lane asc) over the same
// multiset -> selection identical. Softmax fp64. fp64 weights (kw64) are
// stored for the separate conv2_scores kernel (EMIT2 moved out of select).
__device__ inline void bitonic32_desc(double& v, int& l, int slot) {
#pragma unroll
  for (int k = 2; k <= 32; k <<= 1) {
#pragma unroll
    for (int j = k >> 1; j > 0; j >>= 1) {
      double ov = __shfl_xor(v, j);
      int    ol = __shfl_xor(l, j);
      int pslot = slot ^ j;
      bool dirDesc = ((slot & k) == 0);
      bool mineFirst = (v > ov) || (v == ov && l < ol);
      bool keepMine = (dirDesc == (slot < pslot)) ? mineFirst : !mineFirst;
      if (!keepMine) { v = ov; l = ol; }
    }
  }
}

template <int W>
__device__ inline void bitonic_desc(double& v, int& l, int lane) {
#pragma unroll
  for (int k = 2; k <= W; k <<= 1) {
#pragma unroll
    for (int j = k >> 1; j > 0; j >>= 1) {
      double ov = __shfl_xor(v, j);
      int    ol = __shfl_xor(l, j);
      int partner = lane ^ j;
      bool dirDesc = ((lane & k) == 0);
      bool mineFirst = (v > ov) || (v == ov && l < ol);
      bool keepMine = (dirDesc == (lane < partner)) ? mineFirst : !mineFirst;
      if (!keepMine) { v = ov; l = ol; }
    }
  }
}

__global__ __launch_bounds__(256) void select32(const double* __restrict__ as_,
                                                const double* __restrict__ ad_,
                                                const int* __restrict__ row_start,
                                                const int* __restrict__ csr_src,
                                                const int* __restrict__ list,
                                                const int* __restrict__ cnt,
                                                int* __restrict__ ksrc,
                                                float* __restrict__ kw,
                                                double* __restrict__ kw64) {
  const int c = cnt[0];
  const int slot = threadIdx.x & 31;           // position within 32-group
  const int grp  = threadIdx.x >> 5;           // 0..7
  const int nl   = grp >> 2;                   // node-local 0..1
  const int h    = grp & 3;
  const int lane = threadIdx.x & 63;           // absolute lane in wave
  const int gbase = lane & 32;                 // group base within wave
  for (int base = blockIdx.x * 2; base < c; base += gridDim.x * 2) {
    int idx = base + nl;
    bool active = (idx < c);
    int n = active ? list[idx] : 0;
    int rs = row_start[n];
    int deg = active ? (row_start[n + 1] - rs) : 0;   // <=32 by binning
    double adv = ad_[n * H_ + h];
    int kcount = deg < KTOP ? deg : KTOP;

    double v; int sv;
    if (slot < deg) {
      int s = csr_src[rs + slot];
      double a = as_[s * H_ + h] + adv;
      v = (a >= 0.0) ? a : (double)NEG_SLOPE * a;
      sv = s;
    } else {
      v = -INFINITY; sv = -1;
    }
    int l = lane;
    bitonic32_desc(v, l, slot);
    int sid = __shfl(sv, l);

    double m = __shfl(v, gbase);               // slot 0 of group = max
    double ex = (slot < kcount) ? exp(v - m) : 0.0;
    double den = ex;
#pragma unroll
    for (int off = 16; off >= 1; off >>= 1) den += __shfl_xor(den, off);
    double inv = (kcount > 0) ? 1.0 / den : 0.0;
    double wgt = ex * inv;                     // exactly 0.0 beyond kcount

    if (active && slot < KTOP) {
      size_t u = ((size_t)n * H_ + h) * KTOP + slot;
      ksrc[u] = (sid >= 0) ? sid : 0;
      kw[u] = (float)wgt;
      if (kw64) kw64[u] = wgt;
    }
  }
}

__global__ __launch_bounds__(256) void select64(const double* __restrict__ as_,
                                                const double* __restrict__ ad_,
                                                const int* __restrict__ row_start,
                                                const int* __restrict__ csr_src,
                                                const int* __restrict__ list,
                                                const int* __restrict__ cnt,
                                                int* __restrict__ ksrc,
                                                float* __restrict__ kw,
                                                double* __restrict__ kw64) {
  __shared__ int    f_src[H_][16];
  __shared__ double f_w[H_][16];
  const int c = cnt[1];
  int h = threadIdx.x >> 6;
  int lane = threadIdx.x & 63;
  for (int idx = blockIdx.x; idx < c; idx += gridDim.x) {
    int n = list[idx];
    int rs = row_start[n];
    int deg = row_start[n + 1] - rs;
    if (deg > 256) deg = 256;   // safety clamp
    double adv = ad_[n * H_ + h];
    int kcount = deg < KTOP ? deg : KTOP;

    double v; int sid;
    if (deg <= 64) {
      double vv; int sv;
      if (lane < deg) {
        int s = csr_src[rs + lane];
        double a = as_[s * H_ + h] + adv;
        vv = (a >= 0.0) ? a : (double)NEG_SLOPE * a;
        sv = s;
      } else {
        vv = -INFINITY; sv = -1;
      }
      int l = lane;
      bitonic_desc<64>(vv, l, lane);
      v = vv;
      sid = __shfl(sv, l);
    } else {
      double av[4]; int svr[4];
#pragma unroll
      for (int q = 0; q < 4; ++q) {
        int id2 = lane + (q << 6);
        if (id2 < deg) {
          int s = csr_src[rs + id2];
          double a = as_[s * H_ + h] + adv;
          av[q] = (a >= 0.0) ? a : (double)NEG_SLOPE * a;
          svr[q] = s;
        } else {
          av[q] = -INFINITY; svr[q] = -1;
        }
      }
      for (int it = 0; it < kcount; ++it) {
        double best = av[0]; int bq = 0;
#pragma unroll
        for (int q = 1; q < 4; ++q)
          if (av[q] > best) { best = av[q]; bq = q; }
        double bv = best; int bl = lane;
#pragma unroll
        for (int off = 32; off >= 1; off >>= 1) {
          double ov = __shfl_down(bv, off);
          int    ol = __shfl_down(bl, off);
          if (ov > bv || (ov == bv && ol < bl)) { bv = ov; bl = ol; }
        }
        bl = __shfl(bl, 0);
        if (lane == bl) {
          f_src[h][it] = svr[bq];
          f_w[h][it] = best;
          av[bq] = -INFINITY;
        }
      }
      v   = (lane < kcount) ? f_w[h][lane] : -INFINITY;
      sid = (lane < kcount) ? f_src[h][lane] : -1;
    }

    double m = __shfl(v, 0);
    double ex = (lane < kcount) ? exp(v - m) : 0.0;
    double den = ex;
#pragma unroll
    for (int off = 32; off >= 1; off >>= 1) den += __shfl_xor(den, off);
    double inv = (kcount > 0) ? 1.0 / den : 0.0;
    double wgt = ex * inv;

    if (lane < KTOP) {
      size_t u = ((size_t)n * H_ + h) * KTOP + lane;
      ksrc[u] = (sid >= 0) ? sid : 0;
      kw[u] = (float)wgt;
      if (kw64) kw64[u] = wgt;
    }
  }
}

// ====================== conv2 scores (EMIT2 moved out of select) ======================
// a2[n,p] = cst[p] + sum_{h,i} w64[n,h,i] * zz[ksrc[n,h,i]*4+h][p],  p in 0..7
// One node per wave: lane = (p, j) with p=lane>>3 output, j=lane&7 reducer.
// Lane j covers q = j, j+8, .., j+32 (q = h*10+i). 40 distinct zz lines per
// node, touched 8x -> L1 hits; reduce = 3 butterfly stages. fp64 throughout.
__global__ __launch_bounds__(256) void conv2_scores(const int* __restrict__ ksrc,
                                                    const double* __restrict__ kw64,
                                                    const double* __restrict__ zz,
                                                    const double* __restrict__ cst,
                                                    double* __restrict__ as2,
                                                    double* __restrict__ ad2, int n_nodes) {
  int n = (blockIdx.x * 256 + threadIdx.x) >> 6;
  int lane = threadIdx.x & 63;
  if (n >= n_nodes) return;
  int p = lane >> 3, j = lane & 7;
  const int*    sp = ksrc + (size_t)n * H_ * KTOP;
  const double* wp = kw64 + (size_t)n * H_ * KTOP;
  double acc = 0.0;
#pragma unroll
  for (int t = 0; t < 5; ++t) {
    int q = j + t * 8;                 // 0..39
    int h = q / KTOP;
    double w = wp[q];
    int s = sp[q];
    acc += w * zz[((size_t)s * H_ + h) * 8 + p];
  }
#pragma unroll
  for (int off = 4; off >= 1; off >>= 1) acc += __shfl_xor(acc, off);
  if (j == 0) {
    double vo = acc + cst[p];
    if (p < 4) as2[n * H_ + p] = vo;
    else       ad2[n * H_ + (p - 4)] = vo;
  }
}

// ====================== gather/aggregate (one node per wave) ======================
template <int CONCAT>
__global__ __launch_bounds__(256) void gather_agg(const float* __restrict__ xl,
                                                  const int* __restrict__ ksrc,
                                                  const float* __restrict__ kw,
                                                  const float* __restrict__ bias,
                                                  float* __restrict__ out, int n_nodes) {
  int n = (blockIdx.x * 256 + threadIdx.x) >> 6;   // one node per wave
  int lane = threadIdx.x & 63;
  if (n >= n_nodes) return;
  const int*   sp = ksrc + (size_t)n * H_ * KTOP;
  const float* wp = kw   + (size_t)n * H_ * KTOP;
  int ss[H_ * KTOP];
#pragma unroll
  for (int k = 0; k < H_ * KTOP; ++k) ss[k] = sp[k];
  float xv[H_ * KTOP];
#pragma unroll
  for (int h = 0; h < H_; ++h)
#pragma unroll
    for (int i = 0; i < KTOP; ++i)
      xv[h * KTOP + i] = xl[(size_t)ss[h * KTOP + i] * HC + h * C_ + lane];
  float accs[H_];
#pragma unroll
  for (int h = 0; h < H_; ++h) {
    float a = 0.f;
#pragma unroll
    for (int i = 0; i < KTOP; ++i) a += wp[h * KTOP + i] * xv[h * KTOP + i];
    accs[h] = a;
  }
  if (CONCAT) {
#pragma unroll
    for (int h = 0; h < H_; ++h)
      out[(size_t)n * HC + h * C_ + lane] = accs[h] + bias[h * C_ + lane];
  } else {
    out[(size_t)n * C_ + lane] =
        0.25f * (accs[0] + accs[1] + accs[2] + accs[3]) + bias[lane];
  }
}

// ============================== launcher ==============================
extern "C" void kernel_launch(void* const* d_in, const int* in_sizes, int n_in,
                              void* d_out, int out_size, void* d_ws, size_t ws_size,
                              hipStream_t stream) {
  const float* x      = (const float*)d_in[0];
  const float* W1     = (const float*)d_in[1];
  const float* att_s1 = (const float*)d_in[2];
  const float* att_d1 = (const float*)d_in[3];
  const float* b1     = (const float*)d_in[4];
  const float* W2     = (const float*)d_in[5];
  const float* att_s2 = (const float*)d_in[6];
  const float* att_d2 = (const float*)d_in[7];
  const float* b2     = (const float*)d_in[8];
  const float* Wl1    = (const float*)d_in[9];
  const float* bl1    = (const float*)d_in[10];
  const float* Wl2    = (const float*)d_in[11];
  const float* bl2    = (const float*)d_in[12];
  const int*   eidx   = (const int*)d_in[13];

  const int N_ = in_sizes[0] / F_IN;     // 50000
  const int E_ = in_sizes[13] / 2;       // 800000
  const int* e_src = eidx;
  const int* e_dst = eidx + E_;

  // workspace layout
  char* base = (char*)d_ws;
  size_t off = 0;
  auto alloc = [&](size_t bytes) -> char* {
    char* p = base + off;
    off = (off + bytes + 255) & ~(size_t)255;
    return p;
  };
  float*  xl        = (float*)alloc((size_t)N_ * HC * 4);
  float*  hbuf      = (float*)alloc((size_t)N_ * HC * 4);   // h1; later h2 (N*64)
  double* as1       = (double*)alloc((size_t)N_ * H_ * 8);
  double* ad1       = (double*)alloc((size_t)N_ * H_ * 8);
  double* as2       = (double*)alloc((size_t)N_ * H_ * 8);
  double* ad2       = (double*)alloc((size_t)N_ * H_ * 8);
  double* zz        = (double*)alloc((size_t)N_ * H_ * 8 * 8);  // [s][h][8] packed
  double* wt        = (double*)alloc((size_t)40 * HC * 8);
  double* u2s       = (double*)alloc((size_t)H_ * HC * 8);
  double* u2d       = (double*)alloc((size_t)H_ * HC * 8);
  double* cst       = (double*)alloc((size_t)8 * 8);
  int*    ksrc1     = (int*)alloc((size_t)N_ * H_ * KTOP * 4);
  float*  kw1       = (float*)alloc((size_t)N_ * H_ * KTOP * 4);
  double* kw64_1    = (double*)alloc((size_t)N_ * H_ * KTOP * 8);
  int*    ksrc2     = (int*)alloc((size_t)N_ * H_ * KTOP * 4);
  float*  kw2       = (float*)alloc((size_t)N_ * H_ * KTOP * 4);
  int*    list32    = (int*)alloc((size_t)N_ * 4);
  int*    list64    = (int*)alloc((size_t)N_ * 4);
  int*    cnt       = (int*)alloc((size_t)8 * 4);
  int* counts       = (int*)alloc((size_t)N_ * 4);
  int* row_start    = (int*)alloc((size_t)(N_ + 1) * 4);
  int* wptr         = (int*)alloc((size_t)N_ * 4);
  int* csr_src      = (int*)alloc((size_t)E_ * 4);
  (void)ws_size;
  float* hidbuf  = xl;   // xl dead after gather_agg<0>; N*128 <= N*256 slot

  const int eb = (E_ + 255) / 256;
  const int nb = (N_ + 255) / 256;

  // ---- CSR build + binning ----
  hipMemsetAsync(counts, 0, (size_t)N_ * 4, stream);
  hipMemsetAsync(cnt, 0, 32, stream);
  count_edges<<<eb, 256, 0, stream>>>(e_dst, E_, counts);
  scan_offsets<<<1, SCAN_T, 0, stream>>>(counts, N_, row_start, wptr, E_);
  scatter_edges<<<eb, 256, 0, stream>>>(e_src, e_dst, E_, wptr, csr_src);
  bin_nodes<<<nb, 256, 0, stream>>>(row_start, N_, list32, list64, cnt);

  // ---- fp64 score folds + score GEMM ----
  fold_att1<<<(H_ * HC + 255) / 256, 256, 0, stream>>>(W1, att_s1, att_d1, wt);
  fold_att2<<<(H_ * HC + 255) / 256, 256, 0, stream>>>(W2, att_s2, att_d2, u2s, u2d);
  fold_vv<<<(8200 + 255) / 256, 256, 0, stream>>>(W1, u2s, u2d, b1, wt, cst);
  scores_gemm<<<(N_ + SNB - 1) / SNB, 256, 0, stream>>>(x, wt, as1, ad1, zz, N_);

  // ---- conv1 GEMM (independent of selection) ----
  dim3 ggrid((N_ + BM - 1) / BM, HC / BN);
  gemm_nt<<<ggrid, 256, 0, stream>>>(x, W1, xl, N_, F_IN, HC);

  // ---- selection conv1 (binned) + exact conv2 scores ----
  select32<<<6250, 256, 0, stream>>>(as1, ad1, row_start, csr_src, list32, cnt,
                                     ksrc1, kw1, kw64_1);
  select64<<<1024, 256, 0, stream>>>(as1, ad1, row_start, csr_src, list64, cnt,
                                     ksrc1, kw1, kw64_1);
  conv2_scores<<<(N_ + 3) / 4, 256, 0, stream>>>(ksrc1, kw64_1, zz, cst, as2, ad2, N_);

  // ---- selection conv2 (binned; no fp64 weight output needed) ----
  select32<<<6250, 256, 0, stream>>>(as2, ad2, row_start, csr_src, list32, cnt,
                                     ksrc2, kw2, nullptr);
  select64<<<1024, 256, 0, stream>>>(as2, ad2, row_start, csr_src, list64, cnt,
                                     ksrc2, kw2, nullptr);

  const int agg_blocks = (N_ + 3) / 4;   // one node per 64-lane wave

  // ---- conv1 aggregate ----
  gather_agg<1><<<agg_blocks, 256, 0, stream>>>(xl, ksrc1, kw1, b1, hbuf, N_);

  // ---- conv2 ----
  gemm_nt<<<ggrid, 256, 0, stream>>>(hbuf, W2, xl, N_, HC, HC);
  gather_agg<0><<<agg_blocks, 256, 0, stream>>>(xl, ksrc2, kw2, b2, hbuf, N_);

  // ---- MLP head ----
  dim3 hgrid((N_ + BM - 1) / BM, 1);
  gemm_bias_relu<<<hgrid, 256, 0, stream>>>(hbuf, Wl1, bl1, hidbuf, N_, C_, 128);
  head_out<<<(N_ * 16 + 255) / 256, 256, 0, stream>>>(hidbuf, Wl2, bl2, (float*)d_out, N_);
}

// Round 8
// 959.089 us; speedup vs baseline: 1.6099x; 1.6099x over previous
//
#include <hip/hip_runtime.h>
#include <math.h>

#define F_IN 256
#define HC   256   // H*C
#define H_   4
#define C_   64
#define KTOP 10
#define NEG_SLOPE 0.2f

// ================= GEMM: C[M,No] = A[M,K] @ B[No,K]^T (fp32) =================
#define BM 128
#define BN 128
#define BK 16
#define LDP (BM + 4)
__global__ __launch_bounds__(256) void gemm_nt(const float* __restrict__ A,
                                               const float* __restrict__ B,
                                               float* __restrict__ Cc,
                                               int M, int K, int No) {
  __shared__ float As[BK][LDP];
  __shared__ float Bs[BK][LDP];
  const int bm = blockIdx.x * BM;
  const int bn = blockIdx.y * BN;
  const int tid = threadIdx.x;
  const int tx = tid & 15, ty = tid >> 4;
  const int lrow = tid >> 1;
  const int lk   = (tid & 1) << 3;
  const bool arow_ok = (bm + lrow < M);
  const float* aptr = A + (size_t)(bm + lrow) * K + lk;
  const float* bptr = B + (size_t)(bn + lrow) * K + lk;
  float acc[8][8] = {};
  for (int k0 = 0; k0 < K; k0 += BK) {
    float4 a0 = make_float4(0.f, 0.f, 0.f, 0.f), a1 = a0;
    if (arow_ok) {
      const float* ap = aptr + k0;
      a0 = *(const float4*)ap;
      a1 = *(const float4*)(ap + 4);
    }
    const float* bp = bptr + k0;
    float4 b0 = *(const float4*)bp;
    float4 b1 = *(const float4*)(bp + 4);
    __syncthreads();
    As[lk + 0][lrow] = a0.x; As[lk + 1][lrow] = a0.y; As[lk + 2][lrow] = a0.z; As[lk + 3][lrow] = a0.w;
    As[lk + 4][lrow] = a1.x; As[lk + 5][lrow] = a1.y; As[lk + 6][lrow] = a1.z; As[lk + 7][lrow] = a1.w;
    Bs[lk + 0][lrow] = b0.x; Bs[lk + 1][lrow] = b0.y; Bs[lk + 2][lrow] = b0.z; Bs[lk + 3][lrow] = b0.w;
    Bs[lk + 4][lrow] = b1.x; Bs[lk + 5][lrow] = b1.y; Bs[lk + 6][lrow] = b1.z; Bs[lk + 7][lrow] = b1.w;
    __syncthreads();
#pragma unroll
    for (int kk = 0; kk < BK; ++kk) {
      float a[8];
      *(float4*)&a[0] = *(const float4*)&As[kk][ty * 8];
      *(float4*)&a[4] = *(const float4*)&As[kk][ty * 8 + 4];
      {
        float4 bv = *(const float4*)&Bs[kk][tx * 4];
#pragma unroll
        for (int i = 0; i < 8; ++i) {
          acc[i][0] += a[i] * bv.x; acc[i][1] += a[i] * bv.y;
          acc[i][2] += a[i] * bv.z; acc[i][3] += a[i] * bv.w;
        }
      }
      {
        float4 bv = *(const float4*)&Bs[kk][64 + tx * 4];
#pragma unroll
        for (int i = 0; i < 8; ++i) {
          acc[i][4] += a[i] * bv.x; acc[i][5] += a[i] * bv.y;
          acc[i][6] += a[i] * bv.z; acc[i][7] += a[i] * bv.w;
        }
      }
    }
  }
#pragma unroll
  for (int i = 0; i < 8; ++i) {
    int r = bm + ty * 8 + i;
    if (r < M) {
      float* cp = Cc + (size_t)r * No + bn;
      *(float4*)(cp + tx * 4) = make_float4(acc[i][0], acc[i][1], acc[i][2], acc[i][3]);
      *(float4*)(cp + 64 + tx * 4) = make_float4(acc[i][4], acc[i][5], acc[i][6], acc[i][7]);
    }
  }
}

// ============ MLP layer 1: hid = relu(A @ B^T + bias), same tiling ============
__global__ __launch_bounds__(256) void gemm_bias_relu(const float* __restrict__ A,
                                                      const float* __restrict__ B,
                                                      const float* __restrict__ bias,
                                                      float* __restrict__ Cc,
                                                      int M, int K, int No) {
  __shared__ float As[BK][LDP];
  __shared__ float Bs[BK][LDP];
  const int bm = blockIdx.x * BM;
  const int bn = blockIdx.y * BN;
  const int tid = threadIdx.x;
  const int tx = tid & 15, ty = tid >> 4;
  const int lrow = tid >> 1;
  const int lk   = (tid & 1) << 3;
  const bool arow_ok = (bm + lrow < M);
  const bool brow_ok = (bn + lrow < No);
  const float* aptr = A + (size_t)(bm + lrow) * K + lk;
  const float* bptr = B + (size_t)(bn + lrow) * K + lk;
  float acc[8][8] = {};
  for (int k0 = 0; k0 < K; k0 += BK) {
    float4 a0 = make_float4(0.f, 0.f, 0.f, 0.f), a1 = a0, b0 = a0, b1 = a0;
    if (arow_ok) {
      const float* ap = aptr + k0;
      a0 = *(const float4*)ap;
      a1 = *(const float4*)(ap + 4);
    }
    if (brow_ok) {
      const float* bp = bptr + k0;
      b0 = *(const float4*)bp;
      b1 = *(const float4*)(bp + 4);
    }
    __syncthreads();
    As[lk + 0][lrow] = a0.x; As[lk + 1][lrow] = a0.y; As[lk + 2][lrow] = a0.z; As[lk + 3][lrow] = a0.w;
    As[lk + 4][lrow] = a1.x; As[lk + 5][lrow] = a1.y; As[lk + 6][lrow] = a1.z; As[lk + 7][lrow] = a1.w;
    Bs[lk + 0][lrow] = b0.x; Bs[lk + 1][lrow] = b0.y; Bs[lk + 2][lrow] = b0.z; Bs[lk + 3][lrow] = b0.w;
    Bs[lk + 4][lrow] = b1.x; Bs[lk + 5][lrow] = b1.y; Bs[lk + 6][lrow] = b1.z; Bs[lk + 7][lrow] = b1.w;
    __syncthreads();
#pragma unroll
    for (int kk = 0; kk < BK; ++kk) {
      float a[8];
      *(float4*)&a[0] = *(const float4*)&As[kk][ty * 8];
      *(float4*)&a[4] = *(const float4*)&As[kk][ty * 8 + 4];
      {
        float4 bv = *(const float4*)&Bs[kk][tx * 4];
#pragma unroll
        for (int i = 0; i < 8; ++i) {
          acc[i][0] += a[i] * bv.x; acc[i][1] += a[i] * bv.y;
          acc[i][2] += a[i] * bv.z; acc[i][3] += a[i] * bv.w;
        }
      }
      {
        float4 bv = *(const float4*)&Bs[kk][64 + tx * 4];
#pragma unroll
        for (int i = 0; i < 8; ++i) {
          acc[i][4] += a[i] * bv.x; acc[i][5] += a[i] * bv.y;
          acc[i][6] += a[i] * bv.z; acc[i][7] += a[i] * bv.w;
        }
      }
    }
  }
#pragma unroll
  for (int i = 0; i < 8; ++i) {
    int r = bm + ty * 8 + i;
    if (r < M) {
      float* cp = Cc + (size_t)r * No + bn;
#pragma unroll
      for (int j = 0; j < 4; ++j) {
        int col = tx * 4 + j;
        cp[col] = fmaxf(acc[i][j] + bias[bn + col], 0.f);
      }
#pragma unroll
      for (int j = 0; j < 4; ++j) {
        int col = 64 + tx * 4 + j;
        cp[col] = fmaxf(acc[i][4 + j] + bias[bn + col], 0.f);
      }
    }
  }
}

// ============ MLP layer 2: out[n,o] = <hid[n,:], Wl2[o,:]> + bl2[o] ============
__global__ __launch_bounds__(256) void head_out(const float* __restrict__ hid,
                                                const float* __restrict__ Wl2,
                                                const float* __restrict__ bl2,
                                                float* __restrict__ out, int n_nodes) {
  int t = blockIdx.x * 256 + threadIdx.x;
  int n = t >> 4, o = t & 15;
  if (n >= n_nodes) return;
  const float4* hp = (const float4*)(hid + (size_t)n * 128);
  const float4* wp = (const float4*)(Wl2 + (size_t)o * 128);
  float acc = bl2[o];
#pragma unroll
  for (int k = 0; k < 32; ++k) {
    float4 hv = hp[k], wv = wp[k];
    acc += hv.x * wv.x + hv.y * wv.y + hv.z * wv.z + hv.w * wv.w;
  }
  out[(size_t)n * 16 + o] = acc;
}

// =========== exact (fp64) attention-score folds, both convs ===========
__global__ __launch_bounds__(256) void fold_att1(const float* __restrict__ W1,
                                                 const float* __restrict__ att_s,
                                                 const float* __restrict__ att_d,
                                                 double* __restrict__ wt) {
  int t = blockIdx.x * 256 + threadIdx.x;   // t = h*HC + k, total 1024
  if (t >= H_ * HC) return;
  int h = t >> 8;
  int k = t & (HC - 1);
  double s = 0.0, d = 0.0;
#pragma unroll 4
  for (int c = 0; c < C_; ++c) {
    double w = (double)W1[(size_t)(h * C_ + c) * HC + k];
    s += w * (double)att_s[h * C_ + c];
    d += w * (double)att_d[h * C_ + c];
  }
  wt[(size_t)(2 * h + 0) * HC + k] = s;
  wt[(size_t)(2 * h + 1) * HC + k] = d;
}

__global__ __launch_bounds__(256) void fold_att2(const float* __restrict__ W2,
                                                 const float* __restrict__ att_s,
                                                 const float* __restrict__ att_d,
                                                 double* __restrict__ u_s,
                                                 double* __restrict__ u_d) {
  int t = blockIdx.x * 256 + threadIdx.x;
  if (t >= H_ * HC) return;
  int h = t >> 8;
  int k = t & (HC - 1);
  double s = 0.0, d = 0.0;
#pragma unroll 4
  for (int c = 0; c < C_; ++c) {
    double w = (double)W2[(size_t)(h * C_ + c) * HC + k];
    s += w * (double)att_s[h * C_ + c];
    d += w * (double)att_d[h * C_ + c];
  }
  u_s[t] = s;
  u_d[t] = d;
}

// vv -> wt rows 8..39, plus cst[8] (cst[0..3]=s, cst[4..7]=d)
__global__ __launch_bounds__(256) void fold_vv(const float* __restrict__ W1,
                                               const double* __restrict__ u2s,
                                               const double* __restrict__ u2d,
                                               const float* __restrict__ b1,
                                               double* __restrict__ wt,
                                               double* __restrict__ cst) {
  int t = blockIdx.x * 256 + threadIdx.x;
  if (t < 8192) {
    int type = t >> 12;          // 0=s, 1=d
    int rem = t & 4095;          // hh*256 + j
    int j = rem & 255;
    int hh = rem >> 8;           // h*4 + h'
    int h = hh >> 2, hp = hh & 3;
    const double* u2 = type ? u2d : u2s;
    double acc = 0.0;
#pragma unroll 4
    for (int c = 0; c < C_; ++c)
      acc += (double)W1[(size_t)(h * C_ + c) * HC + j] * u2[hp * HC + h * C_ + c];
    wt[(size_t)(8 + type * 16 + hh) * HC + j] = acc;
  } else if (t < 8200) {
    int q = t - 8192;            // 0..7
    const double* u2 = (q >> 2) ? u2d : u2s;
    int hp = q & 3;
    double acc = 0.0;
    for (int k = 0; k < HC; ++k) acc += (double)b1[k] * u2[hp * HC + k];
    cst[q] = acc;
  }
}

// ====== score GEMM — C[N,40] = x[N,256] . wt[40,256]^T, fp64 acc ======
#define SNB 128
#define SKB 32
__global__ __launch_bounds__(256) void scores_gemm(const float* __restrict__ x,
                                                   const double* __restrict__ wt,
                                                   double* __restrict__ as1,
                                                   double* __restrict__ ad1,
                                                   double* __restrict__ zz, int n_nodes) {
  __shared__ float  Xs[SNB][SKB + 1];
  __shared__ double Ws[40][SKB + 1];
  const int tid = threadIdx.x;
  const int n0 = blockIdx.x * SNB;
  const int g = tid & 3;
  const int p = tid >> 2;
  double acc0[10] = {}, acc1[10] = {};
  for (int k0 = 0; k0 < HC; k0 += SKB) {
    __syncthreads();
    {
      int row = tid >> 1;
      int colb = (tid & 1) * 16;
      float* d = &Xs[row][colb];
      int n = n0 + row;
      if (n < n_nodes) {
        const float* xp = x + (size_t)n * HC + k0 + colb;
        float4 v0 = *(const float4*)(xp);
        float4 v1 = *(const float4*)(xp + 4);
        float4 v2 = *(const float4*)(xp + 8);
        float4 v3 = *(const float4*)(xp + 12);
        d[0] = v0.x;  d[1] = v0.y;  d[2] = v0.z;  d[3] = v0.w;
        d[4] = v1.x;  d[5] = v1.y;  d[6] = v1.z;  d[7] = v1.w;
        d[8] = v2.x;  d[9] = v2.y;  d[10] = v2.z; d[11] = v2.w;
        d[12] = v3.x; d[13] = v3.y; d[14] = v3.z; d[15] = v3.w;
      } else {
#pragma unroll
        for (int j = 0; j < 16; ++j) d[j] = 0.f;
      }
    }
#pragma unroll
    for (int q = 0; q < 5; ++q) {
      int idx = tid + q * 256;
      int row = idx >> 5, col = idx & 31;
      Ws[row][col] = wt[(size_t)row * HC + k0 + col];
    }
    __syncthreads();
#pragma unroll
    for (int kk = 0; kk < SKB; ++kk) {
      double xv0 = (double)Xs[2 * p][kk];
      double xv1 = (double)Xs[2 * p + 1][kk];
#pragma unroll
      for (int ci = 0; ci < 10; ++ci) {
        double w = Ws[g * 10 + ci][kk];
        acc0[ci] += xv0 * w;
        acc1[ci] += xv1 * w;
      }
    }
  }
  const int na = n0 + 2 * p;
  const int nb = na + 1;
  if (na < n_nodes) {
#pragma unroll
    for (int ci = 0; ci < 10; ++ci) {
      int c = g * 10 + ci;
      double v = acc0[ci];
      if (c < 8)       ((c & 1) ? ad1 : as1)[na * H_ + (c >> 1)] = v;
      else if (c < 24) { int hh = c - 8;  zz[((size_t)na * H_ + (hh >> 2)) * 8 + (hh & 3)] = v; }
      else             { int hh = c - 24; zz[((size_t)na * H_ + (hh >> 2)) * 8 + 4 + (hh & 3)] = v; }
    }
  }
  if (nb < n_nodes) {
#pragma unroll
    for (int ci = 0; ci < 10; ++ci) {
      int c = g * 10 + ci;
      double v = acc1[ci];
      if (c < 8)       ((c & 1) ? ad1 : as1)[nb * H_ + (c >> 1)] = v;
      else if (c < 24) { int hh = c - 8;  zz[((size_t)nb * H_ + (hh >> 2)) * 8 + (hh & 3)] = v; }
      else             { int hh = c - 24; zz[((size_t)nb * H_ + (hh >> 2)) * 8 + 4 + (hh & 3)] = v; }
    }
  }
}

// ====================== CSR build + big-node list ======================
__global__ void count_edges(const int* __restrict__ dst, int E_, int* __restrict__ counts) {
  int e = blockIdx.x * blockDim.x + threadIdx.x;
  if (e < E_) atomicAdd(&counts[dst[e]], 1);
}

#define SCAN_T 1024
__global__ __launch_bounds__(SCAN_T) void scan_offsets(const int* __restrict__ counts,
                                                       int n_nodes, int* __restrict__ row_start,
                                                       int* __restrict__ wptr, int E_) {
  __shared__ int part[SCAN_T];
  int t = threadIdx.x;
  int chunk = (n_nodes + SCAN_T - 1) / SCAN_T;
  int lo = t * chunk;
  int hi = lo + chunk; if (hi > n_nodes) hi = n_nodes;
  int s = 0;
  for (int i = lo; i < hi; ++i) s += counts[i];
  part[t] = s;
  __syncthreads();
  for (int off = 1; off < SCAN_T; off <<= 1) {
    int v = (t >= off) ? part[t - off] : 0;
    __syncthreads();
    part[t] += v;
    __syncthreads();
  }
  int run = part[t] - s;
  for (int i = lo; i < hi; ++i) {
    int c = counts[i];
    row_start[i] = run;
    wptr[i] = run;
    run += c;
  }
  if (t == SCAN_T - 1) row_start[n_nodes] = E_;
}

__global__ void scatter_edges(const int* __restrict__ src, const int* __restrict__ dst, int E_,
                              int* __restrict__ wptr, int* __restrict__ csr_src) {
  int e = blockIdx.x * blockDim.x + threadIdx.x;
  if (e < E_) {
    int p = atomicAdd(&wptr[dst[e]], 1);
    csr_src[p] = src[e];
  }
}

// R19: only the rare big nodes (deg>32, ~1e-4 of N) go through an atomic.
// R7's bin_nodes did 50000 serialized same-address atomicAdds = 568us.
__global__ void bin_big(const int* __restrict__ row_start, int n_nodes,
                        int* __restrict__ list64, int* __restrict__ cnt) {
  int n = blockIdx.x * blockDim.x + threadIdx.x;
  if (n >= n_nodes) return;
  int deg = row_start[n + 1] - row_start[n];
  if (deg > 32) { int p = atomicAdd(&cnt[1], 1); list64[p] = n; }
}

// ====================== top-K select (degree-binned) ======================
// deg<=32 nodes: 32-lane-group bitonic, 2 (node,head) items per wave inst.
// Same fp64 comparator (v desc, lane asc) over the same candidate multiset
// -> selection identical to the 64-wide sort. Softmax fp64. kw64 stored for
// the separate conv2_scores kernel.
__device__ inline void bitonic32_desc(double& v, int& l, int slot) {
#pragma unroll
  for (int k = 2; k <= 32; k <<= 1) {
#pragma unroll
    for (int j = k >> 1; j > 0; j >>= 1) {
      double ov = __shfl_xor(v, j);
      int    ol = __shfl_xor(l, j);
      int pslot = slot ^ j;
      bool dirDesc = ((slot & k) == 0);
      bool mineFirst = (v > ov) || (v == ov && l < ol);
      bool keepMine = (dirDesc == (slot < pslot)) ? mineFirst : !mineFirst;
      if (!keepMine) { v = ov; l = ol; }
    }
  }
}

template <int W>
__device__ inline void bitonic_desc(double& v, int& l, int lane) {
#pragma unroll
  for (int k = 2; k <= W; k <<= 1) {
#pragma unroll
    for (int j = k >> 1; j > 0; j >>= 1) {
      double ov = __shfl_xor(v, j);
      int    ol = __shfl_xor(l, j);
      int partner = lane ^ j;
      bool dirDesc = ((lane & k) == 0);
      bool mineFirst = (v > ov) || (v == ov && l < ol);
      bool keepMine = (dirDesc == (lane < partner)) ? mineFirst : !mineFirst;
      if (!keepMine) { v = ov; l = ol; }
    }
  }
}

// iterates node ids directly (no list); skips deg>32 (handled by select64)
__global__ __launch_bounds__(256) void select32(const double* __restrict__ as_,
                                                const double* __restrict__ ad_,
                                                const int* __restrict__ row_start,
                                                const int* __restrict__ csr_src,
                                                int n_nodes,
                                                int* __restrict__ ksrc,
                                                float* __restrict__ kw,
                                                double* __restrict__ kw64) {
  const int slot = threadIdx.x & 31;           // position within 32-group
  const int grp  = threadIdx.x >> 5;           // 0..7
  const int nl   = grp >> 2;                   // node-local 0..1
  const int h    = grp & 3;
  const int lane = threadIdx.x & 63;           // absolute lane in wave
  const int gbase = lane & 32;                 // group base within wave
  for (int base = blockIdx.x * 2; base < n_nodes; base += gridDim.x * 2) {
    int n = base + nl;
    bool active = (n < n_nodes);
    int nn = active ? n : 0;
    int rs = row_start[nn];
    int deg = active ? (row_start[nn + 1] - rs) : 0;
    if (deg > 32) { active = false; deg = 0; }   // big nodes -> select64
    double adv = ad_[nn * H_ + h];
    int kcount = deg < KTOP ? deg : KTOP;

    double v; int sv;
    if (slot < deg) {
      int s = csr_src[rs + slot];
      double a = as_[s * H_ + h] + adv;
      v = (a >= 0.0) ? a : (double)NEG_SLOPE * a;
      sv = s;
    } else {
      v = -INFINITY; sv = -1;
    }
    int l = lane;
    bitonic32_desc(v, l, slot);
    int sid = __shfl(sv, l);

    double m = __shfl(v, gbase);               // slot 0 of group = max
    double ex = (slot < kcount) ? exp(v - m) : 0.0;
    double den = ex;
#pragma unroll
    for (int off = 16; off >= 1; off >>= 1) den += __shfl_xor(den, off);
    double inv = (kcount > 0) ? 1.0 / den : 0.0;
    double wgt = ex * inv;                     // exactly 0.0 beyond kcount

    if (active && slot < KTOP) {
      size_t u = ((size_t)n * H_ + h) * KTOP + slot;
      ksrc[u] = (sid >= 0) ? sid : 0;
      kw[u] = (float)wgt;
      if (kw64) kw64[u] = wgt;
    }
  }
}

__global__ __launch_bounds__(256) void select64(const double* __restrict__ as_,
                                                const double* __restrict__ ad_,
                                                const int* __restrict__ row_start,
                                                const int* __restrict__ csr_src,
                                                const int* __restrict__ list,
                                                const int* __restrict__ cnt,
                                                int* __restrict__ ksrc,
                                                float* __restrict__ kw,
                                                double* __restrict__ kw64) {
  __shared__ int    f_src[H_][16];
  __shared__ double f_w[H_][16];
  const int c = cnt[1];
  int h = threadIdx.x >> 6;
  int lane = threadIdx.x & 63;
  for (int idx = blockIdx.x; idx < c; idx += gridDim.x) {
    int n = list[idx];
    int rs = row_start[n];
    int deg = row_start[n + 1] - rs;
    if (deg > 256) deg = 256;   // safety clamp
    double adv = ad_[n * H_ + h];
    int kcount = deg < KTOP ? deg : KTOP;

    double v; int sid;
    if (deg <= 64) {
      double vv; int sv;
      if (lane < deg) {
        int s = csr_src[rs + lane];
        double a = as_[s * H_ + h] + adv;
        vv = (a >= 0.0) ? a : (double)NEG_SLOPE * a;
        sv = s;
      } else {
        vv = -INFINITY; sv = -1;
      }
      int l = lane;
      bitonic_desc<64>(vv, l, lane);
      v = vv;
      sid = __shfl(sv, l);
    } else {
      double av[4]; int svr[4];
#pragma unroll
      for (int q = 0; q < 4; ++q) {
        int id2 = lane + (q << 6);
        if (id2 < deg) {
          int s = csr_src[rs + id2];
          double a = as_[s * H_ + h] + adv;
          av[q] = (a >= 0.0) ? a : (double)NEG_SLOPE * a;
          svr[q] = s;
        } else {
          av[q] = -INFINITY; svr[q] = -1;
        }
      }
      for (int it = 0; it < kcount; ++it) {
        double best = av[0]; int bq = 0;
#pragma unroll
        for (int q = 1; q < 4; ++q)
          if (av[q] > best) { best = av[q]; bq = q; }
        double bv = best; int bl = lane;
#pragma unroll
        for (int off = 32; off >= 1; off >>= 1) {
          double ov = __shfl_down(bv, off);
          int    ol = __shfl_down(bl, off);
          if (ov > bv || (ov == bv && ol < bl)) { bv = ov; bl = ol; }
        }
        bl = __shfl(bl, 0);
        if (lane == bl) {
          f_src[h][it] = svr[bq];
          f_w[h][it] = best;
          av[bq] = -INFINITY;
        }
      }
      v   = (lane < kcount) ? f_w[h][lane] : -INFINITY;
      sid = (lane < kcount) ? f_src[h][lane] : -1;
    }

    double m = __shfl(v, 0);
    double ex = (lane < kcount) ? exp(v - m) : 0.0;
    double den = ex;
#pragma unroll
    for (int off = 32; off >= 1; off >>= 1) den += __shfl_xor(den, off);
    double inv = (kcount > 0) ? 1.0 / den : 0.0;
    double wgt = ex * inv;

    if (lane < KTOP) {
      size_t u = ((size_t)n * H_ + h) * KTOP + lane;
      ksrc[u] = (sid >= 0) ? sid : 0;
      kw[u] = (float)wgt;
      if (kw64) kw64[u] = wgt;
    }
  }
}

// ====================== conv2 scores ======================
// a2[n,p] = cst[p] + sum_{h,i} w64[n,h,i] * zz[ksrc[n,h,i]*4+h][p],  p in 0..7
__global__ __launch_bounds__(256) void conv2_scores(const int* __restrict__ ksrc,
                                                    const double* __restrict__ kw64,
                                                    const double* __restrict__ zz,
                                                    const double* __restrict__ cst,
                                                    double* __restrict__ as2,
                                                    double* __restrict__ ad2, int n_nodes) {
  int n = (blockIdx.x * 256 + threadIdx.x) >> 6;
  int lane = threadIdx.x & 63;
  if (n >= n_nodes) return;
  int p = lane >> 3, j = lane & 7;
  const int*    sp = ksrc + (size_t)n * H_ * KTOP;
  const double* wp = kw64 + (size_t)n * H_ * KTOP;
  double acc = 0.0;
#pragma unroll
  for (int t = 0; t < 5; ++t) {
    int q = j + t * 8;                 // 0..39
    int h = q / KTOP;
    double w = wp[q];
    int s = sp[q];
    acc += w * zz[((size_t)s * H_ + h) * 8 + p];
  }
#pragma unroll
  for (int off = 4; off >= 1; off >>= 1) acc += __shfl_xor(acc, off);
  if (j == 0) {
    double vo = acc + cst[p];
    if (p < 4) as2[n * H_ + p] = vo;
    else       ad2[n * H_ + (p - 4)] = vo;
  }
}

// ====================== gather/aggregate (one node per wave) ======================
template <int CONCAT>
__global__ __launch_bounds__(256) void gather_agg(const float* __restrict__ xl,
                                                  const int* __restrict__ ksrc,
                                                  const float* __restrict__ kw,
                                                  const float* __restrict__ bias,
                                                  float* __restrict__ out, int n_nodes) {
  int n = (blockIdx.x * 256 + threadIdx.x) >> 6;   // one node per wave
  int lane = threadIdx.x & 63;
  if (n >= n_nodes) return;
  const int*   sp = ksrc + (size_t)n * H_ * KTOP;
  const float* wp = kw   + (size_t)n * H_ * KTOP;
  int ss[H_ * KTOP];
#pragma unroll
  for (int k = 0; k < H_ * KTOP; ++k) ss[k] = sp[k];
  float xv[H_ * KTOP];
#pragma unroll
  for (int h = 0; h < H_; ++h)
#pragma unroll
    for (int i = 0; i < KTOP; ++i)
      xv[h * KTOP + i] = xl[(size_t)ss[h * KTOP + i] * HC + h * C_ + lane];
  float accs[H_];
#pragma unroll
  for (int h = 0; h < H_; ++h) {
    float a = 0.f;
#pragma unroll
    for (int i = 0; i < KTOP; ++i) a += wp[h * KTOP + i] * xv[h * KTOP + i];
    accs[h] = a;
  }
  if (CONCAT) {
#pragma unroll
    for (int h = 0; h < H_; ++h)
      out[(size_t)n * HC + h * C_ + lane] = accs[h] + bias[h * C_ + lane];
  } else {
    out[(size_t)n * C_ + lane] =
        0.25f * (accs[0] + accs[1] + accs[2] + accs[3]) + bias[lane];
  }
}

// ============================== launcher ==============================
extern "C" void kernel_launch(void* const* d_in, const int* in_sizes, int n_in,
                              void* d_out, int out_size, void* d_ws, size_t ws_size,
                              hipStream_t stream) {
  const float* x      = (const float*)d_in[0];
  const float* W1     = (const float*)d_in[1];
  const float* att_s1 = (const float*)d_in[2];
  const float* att_d1 = (const float*)d_in[3];
  const float* b1     = (const float*)d_in[4];
  const float* W2     = (const float*)d_in[5];
  const float* att_s2 = (const float*)d_in[6];
  const float* att_d2 = (const float*)d_in[7];
  const float* b2     = (const float*)d_in[8];
  const float* Wl1    = (const float*)d_in[9];
  const float* bl1    = (const float*)d_in[10];
  const float* Wl2    = (const float*)d_in[11];
  const float* bl2    = (const float*)d_in[12];
  const int*   eidx   = (const int*)d_in[13];

  const int N_ = in_sizes[0] / F_IN;     // 50000
  const int E_ = in_sizes[13] / 2;       // 800000
  const int* e_src = eidx;
  const int* e_dst = eidx + E_;

  // workspace layout
  char* base = (char*)d_ws;
  size_t off = 0;
  auto alloc = [&](size_t bytes) -> char* {
    char* p = base + off;
    off = (off + bytes + 255) & ~(size_t)255;
    return p;
  };
  float*  xl        = (float*)alloc((size_t)N_ * HC * 4);
  float*  hbuf      = (float*)alloc((size_t)N_ * HC * 4);   // h1; later h2 (N*64)
  double* as1       = (double*)alloc((size_t)N_ * H_ * 8);
  double* ad1       = (double*)alloc((size_t)N_ * H_ * 8);
  double* as2       = (double*)alloc((size_t)N_ * H_ * 8);
  double* ad2       = (double*)alloc((size_t)N_ * H_ * 8);
  double* zz        = (double*)alloc((size_t)N_ * H_ * 8 * 8);  // [s][h][8] packed
  double* wt        = (double*)alloc((size_t)40 * HC * 8);
  double* u2s       = (double*)alloc((size_t)H_ * HC * 8);
  double* u2d       = (double*)alloc((size_t)H_ * HC * 8);
  double* cst       = (double*)alloc((size_t)8 * 8);
  int*    ksrc1     = (int*)alloc((size_t)N_ * H_ * KTOP * 4);
  float*  kw1       = (float*)alloc((size_t)N_ * H_ * KTOP * 4);
  double* kw64_1    = (double*)alloc((size_t)N_ * H_ * KTOP * 8);
  int*    ksrc2     = (int*)alloc((size_t)N_ * H_ * KTOP * 4);
  float*  kw2       = (float*)alloc((size_t)N_ * H_ * KTOP * 4);
  int*    list64    = (int*)alloc((size_t)N_ * 4);
  int*    cnt       = (int*)alloc((size_t)8 * 4);
  int* counts       = (int*)alloc((size_t)N_ * 4);
  int* row_start    = (int*)alloc((size_t)(N_ + 1) * 4);
  int* wptr         = (int*)alloc((size_t)N_ * 4);
  int* csr_src      = (int*)alloc((size_t)E_ * 4);
  (void)ws_size;
  float* hidbuf  = xl;   // xl dead after gather_agg<0>; N*128 <= N*256 slot

  const int eb = (E_ + 255) / 256;
  const int nb = (N_ + 255) / 256;

  // ---- CSR build + big-node list ----
  hipMemsetAsync(counts, 0, (size_t)N_ * 4, stream);
  hipMemsetAsync(cnt, 0, 32, stream);
  count_edges<<<eb, 256, 0, stream>>>(e_dst, E_, counts);
  scan_offsets<<<1, SCAN_T, 0, stream>>>(counts, N_, row_start, wptr, E_);
  scatter_edges<<<eb, 256, 0, stream>>>(e_src, e_dst, E_, wptr, csr_src);
  bin_big<<<nb, 256, 0, stream>>>(row_start, N_, list64, cnt);

  // ---- fp64 score folds + score GEMM ----
  fold_att1<<<(H_ * HC + 255) / 256, 256, 0, stream>>>(W1, att_s1, att_d1, wt);
  fold_att2<<<(H_ * HC + 255) / 256, 256, 0, stream>>>(W2, att_s2, att_d2, u2s, u2d);
  fold_vv<<<(8200 + 255) / 256, 256, 0, stream>>>(W1, u2s, u2d, b1, wt, cst);
  scores_gemm<<<(N_ + SNB - 1) / SNB, 256, 0, stream>>>(x, wt, as1, ad1, zz, N_);

  // ---- conv1 GEMM (independent of selection) ----
  dim3 ggrid((N_ + BM - 1) / BM, HC / BN);
  gemm_nt<<<ggrid, 256, 0, stream>>>(x, W1, xl, N_, F_IN, HC);

  // ---- selection conv1 (binned) + exact conv2 scores ----
  select32<<<6250, 256, 0, stream>>>(as1, ad1, row_start, csr_src, N_, ksrc1, kw1, kw64_1);
  select64<<<1024, 256, 0, stream>>>(as1, ad1, row_start, csr_src, list64, cnt,
                                     ksrc1, kw1, kw64_1);
  conv2_scores<<<(N_ + 3) / 4, 256, 0, stream>>>(ksrc1, kw64_1, zz, cst, as2, ad2, N_);

  // ---- selection conv2 (binned) ----
  select32<<<6250, 256, 0, stream>>>(as2, ad2, row_start, csr_src, N_, ksrc2, kw2, nullptr);
  select64<<<1024, 256, 0, stream>>>(as2, ad2, row_start, csr_src, list64, cnt,
                                     ksrc2, kw2, nullptr);

  const int agg_blocks = (N_ + 3) / 4;   // one node per 64-lane wave

  // ---- conv1 aggregate ----
  gather_agg<1><<<agg_blocks, 256, 0, stream>>>(xl, ksrc1, kw1, b1, hbuf, N_);

  // ---- conv2 ----
  gemm_nt<<<ggrid, 256, 0, stream>>>(hbuf, W2, xl, N_, HC, HC);
  gather_agg<0><<<agg_blocks, 256, 0, stream>>>(xl, ksrc2, kw2, b2, hbuf, N_);

  // ---- MLP head ----
  dim3 hgrid((N_ + BM - 1) / BM, 1);
  gemm_bias_relu<<<hgrid, 256, 0, stream>>>(hbuf, Wl1, bl1, hidbuf, N_, C_, 128);
  head_out<<<(N_ * 16 + 255) / 256, 256, 0, stream>>>(hidbuf, Wl2, bl2, (float*)d_out, N_);
}

// Round 9
// 825.554 us; speedup vs baseline: 1.8703x; 1.1618x over previous
//
#include <hip/hip_runtime.h>
#include <math.h>

#define F_IN 256
#define HC   256   // H*C
#define H_   4
#define C_   64
#define KTOP 10
#define NEG_SLOPE 0.2f

// ================= GEMM: C[M,No] = A[M,K] @ B[No,K]^T (fp32) =================
#define BM 128
#define BN 128
#define BK 16
#define LDP (BM + 4)
__global__ __launch_bounds__(256) void gemm_nt(const float* __restrict__ A,
                                               const float* __restrict__ B,
                                               float* __restrict__ Cc,
                                               int M, int K, int No) {
  __shared__ float As[BK][LDP];
  __shared__ float Bs[BK][LDP];
  const int bm = blockIdx.x * BM;
  const int bn = blockIdx.y * BN;
  const int tid = threadIdx.x;
  const int tx = tid & 15, ty = tid >> 4;
  const int lrow = tid >> 1;
  const int lk   = (tid & 1) << 3;
  const bool arow_ok = (bm + lrow < M);
  const float* aptr = A + (size_t)(bm + lrow) * K + lk;
  const float* bptr = B + (size_t)(bn + lrow) * K + lk;
  float acc[8][8] = {};
  for (int k0 = 0; k0 < K; k0 += BK) {
    float4 a0 = make_float4(0.f, 0.f, 0.f, 0.f), a1 = a0;
    if (arow_ok) {
      const float* ap = aptr + k0;
      a0 = *(const float4*)ap;
      a1 = *(const float4*)(ap + 4);
    }
    const float* bp = bptr + k0;
    float4 b0 = *(const float4*)bp;
    float4 b1 = *(const float4*)(bp + 4);
    __syncthreads();
    As[lk + 0][lrow] = a0.x; As[lk + 1][lrow] = a0.y; As[lk + 2][lrow] = a0.z; As[lk + 3][lrow] = a0.w;
    As[lk + 4][lrow] = a1.x; As[lk + 5][lrow] = a1.y; As[lk + 6][lrow] = a1.z; As[lk + 7][lrow] = a1.w;
    Bs[lk + 0][lrow] = b0.x; Bs[lk + 1][lrow] = b0.y; Bs[lk + 2][lrow] = b0.z; Bs[lk + 3][lrow] = b0.w;
    Bs[lk + 4][lrow] = b1.x; Bs[lk + 5][lrow] = b1.y; Bs[lk + 6][lrow] = b1.z; Bs[lk + 7][lrow] = b1.w;
    __syncthreads();
#pragma unroll
    for (int kk = 0; kk < BK; ++kk) {
      float a[8];
      *(float4*)&a[0] = *(const float4*)&As[kk][ty * 8];
      *(float4*)&a[4] = *(const float4*)&As[kk][ty * 8 + 4];
      {
        float4 bv = *(const float4*)&Bs[kk][tx * 4];
#pragma unroll
        for (int i = 0; i < 8; ++i) {
          acc[i][0] += a[i] * bv.x; acc[i][1] += a[i] * bv.y;
          acc[i][2] += a[i] * bv.z; acc[i][3] += a[i] * bv.w;
        }
      }
      {
        float4 bv = *(const float4*)&Bs[kk][64 + tx * 4];
#pragma unroll
        for (int i = 0; i < 8; ++i) {
          acc[i][4] += a[i] * bv.x; acc[i][5] += a[i] * bv.y;
          acc[i][6] += a[i] * bv.z; acc[i][7] += a[i] * bv.w;
        }
      }
    }
  }
#pragma unroll
  for (int i = 0; i < 8; ++i) {
    int r = bm + ty * 8 + i;
    if (r < M) {
      float* cp = Cc + (size_t)r * No + bn;
      *(float4*)(cp + tx * 4) = make_float4(acc[i][0], acc[i][1], acc[i][2], acc[i][3]);
      *(float4*)(cp + 64 + tx * 4) = make_float4(acc[i][4], acc[i][5], acc[i][6], acc[i][7]);
    }
  }
}

// ============ MLP layer 1: hid = relu(A @ B^T + bias), same tiling ============
__global__ __launch_bounds__(256) void gemm_bias_relu(const float* __restrict__ A,
                                                      const float* __restrict__ B,
                                                      const float* __restrict__ bias,
                                                      float* __restrict__ Cc,
                                                      int M, int K, int No) {
  __shared__ float As[BK][LDP];
  __shared__ float Bs[BK][LDP];
  const int bm = blockIdx.x * BM;
  const int bn = blockIdx.y * BN;
  const int tid = threadIdx.x;
  const int tx = tid & 15, ty = tid >> 4;
  const int lrow = tid >> 1;
  const int lk   = (tid & 1) << 3;
  const bool arow_ok = (bm + lrow < M);
  const bool brow_ok = (bn + lrow < No);
  const float* aptr = A + (size_t)(bm + lrow) * K + lk;
  const float* bptr = B + (size_t)(bn + lrow) * K + lk;
  float acc[8][8] = {};
  for (int k0 = 0; k0 < K; k0 += BK) {
    float4 a0 = make_float4(0.f, 0.f, 0.f, 0.f), a1 = a0, b0 = a0, b1 = a0;
    if (arow_ok) {
      const float* ap = aptr + k0;
      a0 = *(const float4*)ap;
      a1 = *(const float4*)(ap + 4);
    }
    if (brow_ok) {
      const float* bp = bptr + k0;
      b0 = *(const float4*)bp;
      b1 = *(const float4*)(bp + 4);
    }
    __syncthreads();
    As[lk + 0][lrow] = a0.x; As[lk + 1][lrow] = a0.y; As[lk + 2][lrow] = a0.z; As[lk + 3][lrow] = a0.w;
    As[lk + 4][lrow] = a1.x; As[lk + 5][lrow] = a1.y; As[lk + 6][lrow] = a1.z; As[lk + 7][lrow] = a1.w;
    Bs[lk + 0][lrow] = b0.x; Bs[lk + 1][lrow] = b0.y; Bs[lk + 2][lrow] = b0.z; Bs[lk + 3][lrow] = b0.w;
    Bs[lk + 4][lrow] = b1.x; Bs[lk + 5][lrow] = b1.y; Bs[lk + 6][lrow] = b1.z; Bs[lk + 7][lrow] = b1.w;
    __syncthreads();
#pragma unroll
    for (int kk = 0; kk < BK; ++kk) {
      float a[8];
      *(float4*)&a[0] = *(const float4*)&As[kk][ty * 8];
      *(float4*)&a[4] = *(const float4*)&As[kk][ty * 8 + 4];
      {
        float4 bv = *(const float4*)&Bs[kk][tx * 4];
#pragma unroll
        for (int i = 0; i < 8; ++i) {
          acc[i][0] += a[i] * bv.x; acc[i][1] += a[i] * bv.y;
          acc[i][2] += a[i] * bv.z; acc[i][3] += a[i] * bv.w;
        }
      }
      {
        float4 bv = *(const float4*)&Bs[kk][64 + tx * 4];
#pragma unroll
        for (int i = 0; i < 8; ++i) {
          acc[i][4] += a[i] * bv.x; acc[i][5] += a[i] * bv.y;
          acc[i][6] += a[i] * bv.z; acc[i][7] += a[i] * bv.w;
        }
      }
    }
  }
#pragma unroll
  for (int i = 0; i < 8; ++i) {
    int r = bm + ty * 8 + i;
    if (r < M) {
      float* cp = Cc + (size_t)r * No + bn;
#pragma unroll
      for (int j = 0; j < 4; ++j) {
        int col = tx * 4 + j;
        cp[col] = fmaxf(acc[i][j] + bias[bn + col], 0.f);
      }
#pragma unroll
      for (int j = 0; j < 4; ++j) {
        int col = 64 + tx * 4 + j;
        cp[col] = fmaxf(acc[i][4 + j] + bias[bn + col], 0.f);
      }
    }
  }
}

// ============ MLP layer 2: out[n,o] = <hid[n,:], Wl2[o,:]> + bl2[o] ============
__global__ __launch_bounds__(256) void head_out(const float* __restrict__ hid,
                                                const float* __restrict__ Wl2,
                                                const float* __restrict__ bl2,
                                                float* __restrict__ out, int n_nodes) {
  int t = blockIdx.x * 256 + threadIdx.x;
  int n = t >> 4, o = t & 15;
  if (n >= n_nodes) return;
  const float4* hp = (const float4*)(hid + (size_t)n * 128);
  const float4* wp = (const float4*)(Wl2 + (size_t)o * 128);
  float acc = bl2[o];
#pragma unroll
  for (int k = 0; k < 32; ++k) {
    float4 hv = hp[k], wv = wp[k];
    acc += hv.x * wv.x + hv.y * wv.y + hv.z * wv.z + hv.w * wv.w;
  }
  out[(size_t)n * 16 + o] = acc;
}

// =========== exact (fp64) attention-score folds, both convs ===========
__global__ __launch_bounds__(256) void fold_att1(const float* __restrict__ W1,
                                                 const float* __restrict__ att_s,
                                                 const float* __restrict__ att_d,
                                                 double* __restrict__ wt) {
  int t = blockIdx.x * 256 + threadIdx.x;   // t = h*HC + k, total 1024
  if (t >= H_ * HC) return;
  int h = t >> 8;
  int k = t & (HC - 1);
  double s = 0.0, d = 0.0;
#pragma unroll 4
  for (int c = 0; c < C_; ++c) {
    double w = (double)W1[(size_t)(h * C_ + c) * HC + k];
    s += w * (double)att_s[h * C_ + c];
    d += w * (double)att_d[h * C_ + c];
  }
  wt[(size_t)(2 * h + 0) * HC + k] = s;
  wt[(size_t)(2 * h + 1) * HC + k] = d;
}

__global__ __launch_bounds__(256) void fold_att2(const float* __restrict__ W2,
                                                 const float* __restrict__ att_s,
                                                 const float* __restrict__ att_d,
                                                 double* __restrict__ u_s,
                                                 double* __restrict__ u_d) {
  int t = blockIdx.x * 256 + threadIdx.x;
  if (t >= H_ * HC) return;
  int h = t >> 8;
  int k = t & (HC - 1);
  double s = 0.0, d = 0.0;
#pragma unroll 4
  for (int c = 0; c < C_; ++c) {
    double w = (double)W2[(size_t)(h * C_ + c) * HC + k];
    s += w * (double)att_s[h * C_ + c];
    d += w * (double)att_d[h * C_ + c];
  }
  u_s[t] = s;
  u_d[t] = d;
}

// vv -> wt rows 8..39, plus cst[8] (cst[0..3]=s, cst[4..7]=d)
__global__ __launch_bounds__(256) void fold_vv(const float* __restrict__ W1,
                                               const double* __restrict__ u2s,
                                               const double* __restrict__ u2d,
                                               const float* __restrict__ b1,
                                               double* __restrict__ wt,
                                               double* __restrict__ cst) {
  int t = blockIdx.x * 256 + threadIdx.x;
  if (t < 8192) {
    int type = t >> 12;          // 0=s, 1=d
    int rem = t & 4095;          // hh*256 + j
    int j = rem & 255;
    int hh = rem >> 8;           // h*4 + h'
    int h = hh >> 2, hp = hh & 3;
    const double* u2 = type ? u2d : u2s;
    double acc = 0.0;
#pragma unroll 4
    for (int c = 0; c < C_; ++c)
      acc += (double)W1[(size_t)(h * C_ + c) * HC + j] * u2[hp * HC + h * C_ + c];
    wt[(size_t)(8 + type * 16 + hh) * HC + j] = acc;
  } else if (t < 8200) {
    int q = t - 8192;            // 0..7
    const double* u2 = (q >> 2) ? u2d : u2s;
    int hp = q & 3;
    double acc = 0.0;
    for (int k = 0; k < HC; ++k) acc += (double)b1[k] * u2[hp * HC + k];
    cst[q] = acc;
  }
}

// ====== score GEMM — C[N,40] = x[N,256] . wt[40,256]^T, fp64 acc ======
#define SNB 128
#define SKB 32
__global__ __launch_bounds__(256) void scores_gemm(const float* __restrict__ x,
                                                   const double* __restrict__ wt,
                                                   double* __restrict__ as1,
                                                   double* __restrict__ ad1,
                                                   double* __restrict__ zz, int n_nodes) {
  __shared__ float  Xs[SNB][SKB + 1];
  __shared__ double Ws[40][SKB + 1];
  const int tid = threadIdx.x;
  const int n0 = blockIdx.x * SNB;
  const int g = tid & 3;
  const int p = tid >> 2;
  double acc0[10] = {}, acc1[10] = {};
  for (int k0 = 0; k0 < HC; k0 += SKB) {
    __syncthreads();
    {
      int row = tid >> 1;
      int colb = (tid & 1) * 16;
      float* d = &Xs[row][colb];
      int n = n0 + row;
      if (n < n_nodes) {
        const float* xp = x + (size_t)n * HC + k0 + colb;
        float4 v0 = *(const float4*)(xp);
        float4 v1 = *(const float4*)(xp + 4);
        float4 v2 = *(const float4*)(xp + 8);
        float4 v3 = *(const float4*)(xp + 12);
        d[0] = v0.x;  d[1] = v0.y;  d[2] = v0.z;  d[3] = v0.w;
        d[4] = v1.x;  d[5] = v1.y;  d[6] = v1.z;  d[7] = v1.w;
        d[8] = v2.x;  d[9] = v2.y;  d[10] = v2.z; d[11] = v2.w;
        d[12] = v3.x; d[13] = v3.y; d[14] = v3.z; d[15] = v3.w;
      } else {
#pragma unroll
        for (int j = 0; j < 16; ++j) d[j] = 0.f;
      }
    }
#pragma unroll
    for (int q = 0; q < 5; ++q) {
      int idx = tid + q * 256;
      int row = idx >> 5, col = idx & 31;
      Ws[row][col] = wt[(size_t)row * HC + k0 + col];
    }
    __syncthreads();
#pragma unroll
    for (int kk = 0; kk < SKB; ++kk) {
      double xv0 = (double)Xs[2 * p][kk];
      double xv1 = (double)Xs[2 * p + 1][kk];
#pragma unroll
      for (int ci = 0; ci < 10; ++ci) {
        double w = Ws[g * 10 + ci][kk];
        acc0[ci] += xv0 * w;
        acc1[ci] += xv1 * w;
      }
    }
  }
  const int na = n0 + 2 * p;
  const int nb = na + 1;
  if (na < n_nodes) {
#pragma unroll
    for (int ci = 0; ci < 10; ++ci) {
      int c = g * 10 + ci;
      double v = acc0[ci];
      if (c < 8)       ((c & 1) ? ad1 : as1)[na * H_ + (c >> 1)] = v;
      else if (c < 24) { int hh = c - 8;  zz[((size_t)na * H_ + (hh >> 2)) * 8 + (hh & 3)] = v; }
      else             { int hh = c - 24; zz[((size_t)na * H_ + (hh >> 2)) * 8 + 4 + (hh & 3)] = v; }
    }
  }
  if (nb < n_nodes) {
#pragma unroll
    for (int ci = 0; ci < 10; ++ci) {
      int c = g * 10 + ci;
      double v = acc1[ci];
      if (c < 8)       ((c & 1) ? ad1 : as1)[nb * H_ + (c >> 1)] = v;
      else if (c < 24) { int hh = c - 8;  zz[((size_t)nb * H_ + (hh >> 2)) * 8 + (hh & 3)] = v; }
      else             { int hh = c - 24; zz[((size_t)nb * H_ + (hh >> 2)) * 8 + 4 + (hh & 3)] = v; }
    }
  }
}

// ====================== CSR build: multi-block scan (R20) ======================
// R8's single-block scan_offsets was 110.8us (1 workgroup, serial walks).
// 3-phase scan: block-local LDS scan -> 196-entry offset scan -> add. ~10us.
__global__ void count_edges(const int* __restrict__ dst, int E_, int* __restrict__ counts) {
  int e = blockIdx.x * blockDim.x + threadIdx.x;
  if (e < E_) atomicAdd(&counts[dst[e]], 1);
}

#define SCB 256
__global__ __launch_bounds__(SCB) void scan_phase1(const int* __restrict__ counts, int n,
                                                   int* __restrict__ row_start,
                                                   int* __restrict__ bsum) {
  __shared__ int sh[SCB];
  int b = blockIdx.x, t = threadIdx.x;
  int idx = b * SCB + t;
  int v = (idx < n) ? counts[idx] : 0;
  sh[t] = v;
  __syncthreads();
  for (int off = 1; off < SCB; off <<= 1) {
    int u = (t >= off) ? sh[t - off] : 0;
    __syncthreads();
    sh[t] += u;
    __syncthreads();
  }
  if (idx < n) row_start[idx] = sh[t] - v;   // block-local exclusive
  if (t == SCB - 1) bsum[b] = sh[t];
}

__global__ __launch_bounds__(SCB) void scan_phase2(int* __restrict__ bsum, int nb) {
  __shared__ int sh[SCB];
  int t = threadIdx.x;
  int v = (t < nb) ? bsum[t] : 0;
  sh[t] = v;
  __syncthreads();
  for (int off = 1; off < SCB; off <<= 1) {
    int u = (t >= off) ? sh[t - off] : 0;
    __syncthreads();
    sh[t] += u;
    __syncthreads();
  }
  if (t < nb) bsum[t] = sh[t] - v;           // exclusive, in place
}

__global__ __launch_bounds__(SCB) void scan_phase3(int n, const int* __restrict__ bsum,
                                                   int* __restrict__ row_start,
                                                   int* __restrict__ wptr, int E_) {
  int b = blockIdx.x, t = threadIdx.x;
  int idx = b * SCB + t;
  if (idx < n) {
    int r = row_start[idx] + bsum[b];
    row_start[idx] = r;
    wptr[idx] = r;
  } else if (idx == n) {
    row_start[n] = E_;
  }
}

__global__ void scatter_edges(const int* __restrict__ src, const int* __restrict__ dst, int E_,
                              int* __restrict__ wptr, int* __restrict__ csr_src) {
  int e = blockIdx.x * blockDim.x + threadIdx.x;
  if (e < E_) {
    int p = atomicAdd(&wptr[dst[e]], 1);
    csr_src[p] = src[e];
  }
}

// only rare big nodes (deg>32) take an atomic (R19)
__global__ void bin_big(const int* __restrict__ row_start, int n_nodes,
                        int* __restrict__ list64, int* __restrict__ cnt) {
  int n = blockIdx.x * blockDim.x + threadIdx.x;
  if (n >= n_nodes) return;
  int deg = row_start[n + 1] - row_start[n];
  if (deg > 32) { int p = atomicAdd(&cnt[1], 1); list64[p] = n; }
}

// ====================== top-K select (u64-key bitonic, R20) ======================
// Sortable key: monotone double->u64 map, low 5 (or 6) bits replaced by
// (31-slot) tiebreak. One key carries value AND tiebreak -> 2 b32 shuffles
// per stage (was 3: fp64 v + payload lane). Ordering identical to the
// (v desc, lane asc) comparator except for fp64 scores equal to 2^-46
// relative (probability ~1e-8 over all boundaries, below fp64-noise floor).
// Softmax value recovered from truncated key: error 2^-46 -> weight delta
// ~1e-14, invisible. kw64 path unchanged (fp64 softmax).
__device__ inline unsigned long long shfl_xor_u64(unsigned long long x, int m) {
  int lo = __shfl_xor((int)(x & 0xffffffffull), m);
  int hi = __shfl_xor((int)(x >> 32), m);
  return ((unsigned long long)(unsigned int)hi << 32) | (unsigned int)lo;
}
__device__ inline unsigned long long mono_key(double v) {
  unsigned long long u = (unsigned long long)__double_as_longlong(v);
  return (u & 0x8000000000000000ull) ? ~u : (u | 0x8000000000000000ull);
}
__device__ inline double mono_val(unsigned long long k) {
  unsigned long long u = (k & 0x8000000000000000ull) ? (k ^ 0x8000000000000000ull) : ~k;
  return __longlong_as_double((long long)u);
}

// iterates node ids directly; skips deg>32 (handled by select64)
__global__ __launch_bounds__(256) void select32(const double* __restrict__ as_,
                                                const double* __restrict__ ad_,
                                                const int* __restrict__ row_start,
                                                const int* __restrict__ csr_src,
                                                int n_nodes,
                                                int* __restrict__ ksrc,
                                                float* __restrict__ kw,
                                                double* __restrict__ kw64) {
  const int slot = threadIdx.x & 31;           // position within 32-group
  const int grp  = threadIdx.x >> 5;           // 0..7
  const int nl   = grp >> 2;                   // node-local 0..1
  const int h    = grp & 3;
  const int lane = threadIdx.x & 63;           // absolute lane in wave
  const int gbase = lane & 32;                 // group base within wave
  for (int base = blockIdx.x * 2; base < n_nodes; base += gridDim.x * 2) {
    int n = base + nl;
    bool active = (n < n_nodes);
    int nn = active ? n : 0;
    int rs = row_start[nn];
    int deg = active ? (row_start[nn + 1] - rs) : 0;
    if (deg > 32) { active = false; deg = 0; }   // big nodes -> select64
    double adv = ad_[nn * H_ + h];
    int kcount = deg < KTOP ? deg : KTOP;

    unsigned long long key; int sv;
    if (slot < deg) {
      int s = csr_src[rs + slot];
      double a = as_[s * H_ + h] + adv;
      double v = (a >= 0.0) ? a : (double)NEG_SLOPE * a;
      key = (mono_key(v) & ~31ull) | (unsigned long long)(31 - slot);
      sv = s;
    } else {
      key = (mono_key(-INFINITY) & ~31ull) | (unsigned long long)(31 - slot);
      sv = -1;
    }
#pragma unroll
    for (int kk = 2; kk <= 32; kk <<= 1) {
#pragma unroll
      for (int j = kk >> 1; j > 0; j >>= 1) {
        unsigned long long ok = shfl_xor_u64(key, j);
        bool dirDesc = ((slot & kk) == 0);
        bool lower   = ((slot & j) == 0);
        bool mineFirst = key > ok;
        if ((dirDesc == lower) ? !mineFirst : mineFirst) key = ok;
      }
    }
    int wslot = 31 - (int)(key & 31ull);
    int sid = __shfl(sv, gbase + wslot);
    double vrec = mono_val(key & ~31ull);
    double m = __shfl(vrec, gbase);            // slot 0 of group = max
    double ex = (slot < kcount) ? exp(vrec - m) : 0.0;
    double den = ex;
#pragma unroll
    for (int off = 16; off >= 1; off >>= 1) den += __shfl_xor(den, off);
    double inv = (kcount > 0) ? 1.0 / den : 0.0;
    double wgt = ex * inv;                     // exactly 0.0 beyond kcount

    if (active && slot < KTOP) {
      size_t u = ((size_t)n * H_ + h) * KTOP + slot;
      ksrc[u] = (sid >= 0) ? sid : 0;
      kw[u] = (float)wgt;
      if (kw64) kw64[u] = wgt;
    }
  }
}

__global__ __launch_bounds__(256) void select64(const double* __restrict__ as_,
                                                const double* __restrict__ ad_,
                                                const int* __restrict__ row_start,
                                                const int* __restrict__ csr_src,
                                                const int* __restrict__ list,
                                                const int* __restrict__ cnt,
                                                int* __restrict__ ksrc,
                                                float* __restrict__ kw,
                                                double* __restrict__ kw64) {
  __shared__ int    f_src[H_][16];
  __shared__ double f_w[H_][16];
  const int c = cnt[1];
  int h = threadIdx.x >> 6;
  int lane = threadIdx.x & 63;
  for (int idx = blockIdx.x; idx < c; idx += gridDim.x) {
    int n = list[idx];
    int rs = row_start[n];
    int deg = row_start[n + 1] - rs;
    if (deg > 256) deg = 256;   // safety clamp
    double adv = ad_[n * H_ + h];
    int kcount = deg < KTOP ? deg : KTOP;

    double vsel; int sid;
    if (deg <= 64) {
      unsigned long long key; int sv;
      if (lane < deg) {
        int s = csr_src[rs + lane];
        double a = as_[s * H_ + h] + adv;
        double v = (a >= 0.0) ? a : (double)NEG_SLOPE * a;
        key = (mono_key(v) & ~63ull) | (unsigned long long)(63 - lane);
        sv = s;
      } else {
        key = (mono_key(-INFINITY) & ~63ull) | (unsigned long long)(63 - lane);
        sv = -1;
      }
#pragma unroll
      for (int kk = 2; kk <= 64; kk <<= 1) {
#pragma unroll
        for (int j = kk >> 1; j > 0; j >>= 1) {
          unsigned long long ok = shfl_xor_u64(key, j);
          bool dirDesc = ((lane & kk) == 0);
          bool lower   = ((lane & j) == 0);
          bool mineFirst = key > ok;
          if ((dirDesc == lower) ? !mineFirst : mineFirst) key = ok;
        }
      }
      int wslot = 63 - (int)(key & 63ull);
      sid = __shfl(sv, wslot);
      vsel = mono_val(key & ~63ull);
    } else {
      double av[4]; int svr[4];
#pragma unroll
      for (int q = 0; q < 4; ++q) {
        int id2 = lane + (q << 6);
        if (id2 < deg) {
          int s = csr_src[rs + id2];
          double a = as_[s * H_ + h] + adv;
          av[q] = (a >= 0.0) ? a : (double)NEG_SLOPE * a;
          svr[q] = s;
        } else {
          av[q] = -INFINITY; svr[q] = -1;
        }
      }
      for (int it = 0; it < kcount; ++it) {
        double best = av[0]; int bq = 0;
#pragma unroll
        for (int q = 1; q < 4; ++q)
          if (av[q] > best) { best = av[q]; bq = q; }
        double bv = best; int bl = lane;
#pragma unroll
        for (int off = 32; off >= 1; off >>= 1) {
          double ov = __shfl_down(bv, off);
          int    ol = __shfl_down(bl, off);
          if (ov > bv || (ov == bv && ol < bl)) { bv = ov; bl = ol; }
        }
        bl = __shfl(bl, 0);
        if (lane == bl) {
          f_src[h][it] = svr[bq];
          f_w[h][it] = best;
          av[bq] = -INFINITY;
        }
      }
      vsel = (lane < kcount) ? f_w[h][lane] : -INFINITY;
      sid  = (lane < kcount) ? f_src[h][lane] : -1;
    }

    double m = __shfl(vsel, 0);
    double ex = (lane < kcount) ? exp(vsel - m) : 0.0;
    double den = ex;
#pragma unroll
    for (int off = 32; off >= 1; off >>= 1) den += __shfl_xor(den, off);
    double inv = (kcount > 0) ? 1.0 / den : 0.0;
    double wgt = ex * inv;

    if (lane < KTOP) {
      size_t u = ((size_t)n * H_ + h) * KTOP + lane;
      ksrc[u] = (sid >= 0) ? sid : 0;
      kw[u] = (float)wgt;
      if (kw64) kw64[u] = wgt;
    }
  }
}

// ====================== conv2 scores ======================
// a2[n,p] = cst[p] + sum_{h,i} w64[n,h,i] * zz[ksrc[n,h,i]*4+h][p],  p in 0..7
__global__ __launch_bounds__(256) void conv2_scores(const int* __restrict__ ksrc,
                                                    const double* __restrict__ kw64,
                                                    const double* __restrict__ zz,
                                                    const double* __restrict__ cst,
                                                    double* __restrict__ as2,
                                                    double* __restrict__ ad2, int n_nodes) {
  int n = (blockIdx.x * 256 + threadIdx.x) >> 6;
  int lane = threadIdx.x & 63;
  if (n >= n_nodes) return;
  int p = lane >> 3, j = lane & 7;
  const int*    sp = ksrc + (size_t)n * H_ * KTOP;
  const double* wp = kw64 + (size_t)n * H_ * KTOP;
  double acc = 0.0;
#pragma unroll
  for (int t = 0; t < 5; ++t) {
    int q = j + t * 8;                 // 0..39
    int h = q / KTOP;
    double w = wp[q];
    int s = sp[q];
    acc += w * zz[((size_t)s * H_ + h) * 8 + p];
  }
#pragma unroll
  for (int off = 4; off >= 1; off >>= 1) acc += __shfl_xor(acc, off);
  if (j == 0) {
    double vo = acc + cst[p];
    if (p < 4) as2[n * H_ + p] = vo;
    else       ad2[n * H_ + (p - 4)] = vo;
  }
}

// ====================== gather/aggregate (one node per wave) ======================
template <int CONCAT>
__global__ __launch_bounds__(256) void gather_agg(const float* __restrict__ xl,
                                                  const int* __restrict__ ksrc,
                                                  const float* __restrict__ kw,
                                                  const float* __restrict__ bias,
                                                  float* __restrict__ out, int n_nodes) {
  int n = (blockIdx.x * 256 + threadIdx.x) >> 6;   // one node per wave
  int lane = threadIdx.x & 63;
  if (n >= n_nodes) return;
  const int*   sp = ksrc + (size_t)n * H_ * KTOP;
  const float* wp = kw   + (size_t)n * H_ * KTOP;
  int ss[H_ * KTOP];
#pragma unroll
  for (int k = 0; k < H_ * KTOP; ++k) ss[k] = sp[k];
  float xv[H_ * KTOP];
#pragma unroll
  for (int h = 0; h < H_; ++h)
#pragma unroll
    for (int i = 0; i < KTOP; ++i)
      xv[h * KTOP + i] = xl[(size_t)ss[h * KTOP + i] * HC + h * C_ + lane];
  float accs[H_];
#pragma unroll
  for (int h = 0; h < H_; ++h) {
    float a = 0.f;
#pragma unroll
    for (int i = 0; i < KTOP; ++i) a += wp[h * KTOP + i] * xv[h * KTOP + i];
    accs[h] = a;
  }
  if (CONCAT) {
#pragma unroll
    for (int h = 0; h < H_; ++h)
      out[(size_t)n * HC + h * C_ + lane] = accs[h] + bias[h * C_ + lane];
  } else {
    out[(size_t)n * C_ + lane] =
        0.25f * (accs[0] + accs[1] + accs[2] + accs[3]) + bias[lane];
  }
}

// ============================== launcher ==============================
extern "C" void kernel_launch(void* const* d_in, const int* in_sizes, int n_in,
                              void* d_out, int out_size, void* d_ws, size_t ws_size,
                              hipStream_t stream) {
  const float* x      = (const float*)d_in[0];
  const float* W1     = (const float*)d_in[1];
  const float* att_s1 = (const float*)d_in[2];
  const float* att_d1 = (const float*)d_in[3];
  const float* b1     = (const float*)d_in[4];
  const float* W2     = (const float*)d_in[5];
  const float* att_s2 = (const float*)d_in[6];
  const float* att_d2 = (const float*)d_in[7];
  const float* b2     = (const float*)d_in[8];
  const float* Wl1    = (const float*)d_in[9];
  const float* bl1    = (const float*)d_in[10];
  const float* Wl2    = (const float*)d_in[11];
  const float* bl2    = (const float*)d_in[12];
  const int*   eidx   = (const int*)d_in[13];

  const int N_ = in_sizes[0] / F_IN;     // 50000
  const int E_ = in_sizes[13] / 2;       // 800000
  const int* e_src = eidx;
  const int* e_dst = eidx + E_;

  // workspace layout
  char* base = (char*)d_ws;
  size_t off = 0;
  auto alloc = [&](size_t bytes) -> char* {
    char* p = base + off;
    off = (off + bytes + 255) & ~(size_t)255;
    return p;
  };
  float*  xl        = (float*)alloc((size_t)N_ * HC * 4);
  float*  hbuf      = (float*)alloc((size_t)N_ * HC * 4);   // h1; later h2 (N*64)
  double* as1       = (double*)alloc((size_t)N_ * H_ * 8);
  double* ad1       = (double*)alloc((size_t)N_ * H_ * 8);
  double* as2       = (double*)alloc((size_t)N_ * H_ * 8);
  double* ad2       = (double*)alloc((size_t)N_ * H_ * 8);
  double* zz        = (double*)alloc((size_t)N_ * H_ * 8 * 8);  // [s][h][8] packed
  double* wt        = (double*)alloc((size_t)40 * HC * 8);
  double* u2s       = (double*)alloc((size_t)H_ * HC * 8);
  double* u2d       = (double*)alloc((size_t)H_ * HC * 8);
  double* cst       = (double*)alloc((size_t)8 * 8);
  int*    ksrc1     = (int*)alloc((size_t)N_ * H_ * KTOP * 4);
  float*  kw1       = (float*)alloc((size_t)N_ * H_ * KTOP * 4);
  double* kw64_1    = (double*)alloc((size_t)N_ * H_ * KTOP * 8);
  int*    ksrc2     = (int*)alloc((size_t)N_ * H_ * KTOP * 4);
  float*  kw2       = (float*)alloc((size_t)N_ * H_ * KTOP * 4);
  int*    list64    = (int*)alloc((size_t)N_ * 4);
  int*    cnt       = (int*)alloc((size_t)8 * 4);
  int*    bsum      = (int*)alloc((size_t)SCB * 4);
  int* counts       = (int*)alloc((size_t)N_ * 4);
  int* row_start    = (int*)alloc((size_t)(N_ + 1) * 4);
  int* wptr         = (int*)alloc((size_t)N_ * 4);
  int* csr_src      = (int*)alloc((size_t)E_ * 4);
  (void)ws_size;
  float* hidbuf  = xl;   // xl dead after gather_agg<0>; N*128 <= N*256 slot

  const int eb = (E_ + 255) / 256;
  const int nb = (N_ + 255) / 256;
  const int sb = (N_ + 1 + SCB - 1) / SCB;   // covers idx == N_ too (196 <= 256)

  // ---- CSR build (multi-block scan) + big-node list ----
  hipMemsetAsync(counts, 0, (size_t)N_ * 4, stream);
  hipMemsetAsync(cnt, 0, 32, stream);
  count_edges<<<eb, 256, 0, stream>>>(e_dst, E_, counts);
  scan_phase1<<<sb, SCB, 0, stream>>>(counts, N_, row_start, bsum);
  scan_phase2<<<1, SCB, 0, stream>>>(bsum, sb);
  scan_phase3<<<sb, SCB, 0, stream>>>(N_, bsum, row_start, wptr, E_);
  scatter_edges<<<eb, 256, 0, stream>>>(e_src, e_dst, E_, wptr, csr_src);
  bin_big<<<nb, 256, 0, stream>>>(row_start, N_, list64, cnt);

  // ---- fp64 score folds + score GEMM ----
  fold_att1<<<(H_ * HC + 255) / 256, 256, 0, stream>>>(W1, att_s1, att_d1, wt);
  fold_att2<<<(H_ * HC + 255) / 256, 256, 0, stream>>>(W2, att_s2, att_d2, u2s, u2d);
  fold_vv<<<(8200 + 255) / 256, 256, 0, stream>>>(W1, u2s, u2d, b1, wt, cst);
  scores_gemm<<<(N_ + SNB - 1) / SNB, 256, 0, stream>>>(x, wt, as1, ad1, zz, N_);

  // ---- conv1 GEMM (independent of selection) ----
  dim3 ggrid((N_ + BM - 1) / BM, HC / BN);
  gemm_nt<<<ggrid, 256, 0, stream>>>(x, W1, xl, N_, F_IN, HC);

  // ---- selection conv1 (binned) + exact conv2 scores ----
  select32<<<6250, 256, 0, stream>>>(as1, ad1, row_start, csr_src, N_, ksrc1, kw1, kw64_1);
  select64<<<1024, 256, 0, stream>>>(as1, ad1, row_start, csr_src, list64, cnt,
                                     ksrc1, kw1, kw64_1);
  conv2_scores<<<(N_ + 3) / 4, 256, 0, stream>>>(ksrc1, kw64_1, zz, cst, as2, ad2, N_);

  // ---- selection conv2 (binned) ----
  select32<<<6250, 256, 0, stream>>>(as2, ad2, row_start, csr_src, N_, ksrc2, kw2, nullptr);
  select64<<<1024, 256, 0, stream>>>(as2, ad2, row_start, csr_src, list64, cnt,
                                     ksrc2, kw2, nullptr);

  const int agg_blocks = (N_ + 3) / 4;   // one node per 64-lane wave

  // ---- conv1 aggregate ----
  gather_agg<1><<<agg_blocks, 256, 0, stream>>>(xl, ksrc1, kw1, b1, hbuf, N_);

  // ---- conv2 ----
  gemm_nt<<<ggrid, 256, 0, stream>>>(hbuf, W2, xl, N_, HC, HC);
  gather_agg<0><<<agg_blocks, 256, 0, stream>>>(xl, ksrc2, kw2, b2, hbuf, N_);

  // ---- MLP head ----
  dim3 hgrid((N_ + BM - 1) / BM, 1);
  gemm_bias_relu<<<hgrid, 256, 0, stream>>>(hbuf, Wl1, bl1, hidbuf, N_, C_, 128);
  head_out<<<(N_ * 16 + 255) / 256, 256, 0, stream>>>(hidbuf, Wl2, bl2, (float*)d_out, N_);
}

// Round 10
// 716.840 us; speedup vs baseline: 2.1539x; 1.1517x over previous
//
#include <hip/hip_runtime.h>
#include <math.h>

#define F_IN 256
#define HC   256   // H*C
#define H_   4
#define C_   64
#define KTOP 10
#define NEG_SLOPE 0.2f

typedef __attribute__((ext_vector_type(8))) short bf16x8;
typedef __attribute__((ext_vector_type(4))) float f32x4;

// ============ R21: bf16x3 split-MFMA GEMM: C[M,No] = A[M,K] @ B[No,K]^T ============
// Selection exactness is carried by the fp64 score path (scores_gemm/conv2_scores),
// so the VALUE gemm only needs <=4e-3 output error. Split a = hi(bf16)+lo(bf16);
// C = Ah.Bh + Ah.Bl + Al.Bh (dropped Al.Bl ~ 2^-18 rel). fp32 MFMA accumulators.
// LDS frag-interleaved [qp][m][8]: elems 0-3 = k quartet qp*4, elems 4-7 = quartet
// 16+qp*4 -> one conflict-free ds_read_b128 per fragment (16B aligned).
#define GM 128
#define GN 128
#define GK 32
__device__ inline unsigned short f2bf_rn(float f) {
  unsigned u = __float_as_uint(f);
  unsigned r = u + 0x7FFFu + ((u >> 16) & 1u);
  return (unsigned short)(r >> 16);
}
__global__ __launch_bounds__(256) void gemm_nt_mfma(const float* __restrict__ A,
                                                    const float* __restrict__ B,
                                                    float* __restrict__ Cc,
                                                    int M, int K, int No) {
  __shared__ unsigned short Ah[4][128][8], Al[4][128][8];
  __shared__ unsigned short Bh[4][128][8], Bl[4][128][8];
  const int tid = threadIdx.x;
  const int bm = blockIdx.x * GM, bn = blockIdx.y * GN;
  const int r = tid >> 1, half = tid & 1;          // staging: row 0..127, k-half
  const int wid = tid >> 6, lane = tid & 63;
  const int wr = wid >> 1, wc = wid & 1;           // wave -> 64x64 quadrant
  const int qp = lane >> 4, fr = lane & 15;
  const bool arow_ok = (bm + r < M);
  const float* ap = A + (size_t)(bm + r) * K + half * 16;
  const float* bp = B + (size_t)(bn + r) * K + half * 16;
  f32x4 acc[4][4];
#pragma unroll
  for (int i = 0; i < 4; ++i)
#pragma unroll
    for (int j = 0; j < 4; ++j) acc[i][j] = (f32x4){0.f, 0.f, 0.f, 0.f};

  for (int k0 = 0; k0 < K; k0 += GK) {
    float va[16], vb[16];
    if (arow_ok) {
      *(float4*)&va[0]  = *(const float4*)(ap + k0);
      *(float4*)&va[4]  = *(const float4*)(ap + k0 + 4);
      *(float4*)&va[8]  = *(const float4*)(ap + k0 + 8);
      *(float4*)&va[12] = *(const float4*)(ap + k0 + 12);
    } else {
#pragma unroll
      for (int j = 0; j < 16; ++j) va[j] = 0.f;
    }
    *(float4*)&vb[0]  = *(const float4*)(bp + k0);
    *(float4*)&vb[4]  = *(const float4*)(bp + k0 + 4);
    *(float4*)&vb[8]  = *(const float4*)(bp + k0 + 8);
    *(float4*)&vb[12] = *(const float4*)(bp + k0 + 12);
    __syncthreads();   // previous tile's frag reads done
#pragma unroll
    for (int c = 0; c < 4; ++c) {
      ushort4 ha, la, hb, lb;
      {
        float f0 = va[c * 4 + 0], f1 = va[c * 4 + 1], f2 = va[c * 4 + 2], f3 = va[c * 4 + 3];
        ha.x = f2bf_rn(f0); ha.y = f2bf_rn(f1); ha.z = f2bf_rn(f2); ha.w = f2bf_rn(f3);
        la.x = f2bf_rn(f0 - __uint_as_float((unsigned)ha.x << 16));
        la.y = f2bf_rn(f1 - __uint_as_float((unsigned)ha.y << 16));
        la.z = f2bf_rn(f2 - __uint_as_float((unsigned)ha.z << 16));
        la.w = f2bf_rn(f3 - __uint_as_float((unsigned)ha.w << 16));
      }
      {
        float f0 = vb[c * 4 + 0], f1 = vb[c * 4 + 1], f2 = vb[c * 4 + 2], f3 = vb[c * 4 + 3];
        hb.x = f2bf_rn(f0); hb.y = f2bf_rn(f1); hb.z = f2bf_rn(f2); hb.w = f2bf_rn(f3);
        lb.x = f2bf_rn(f0 - __uint_as_float((unsigned)hb.x << 16));
        lb.y = f2bf_rn(f1 - __uint_as_float((unsigned)hb.y << 16));
        lb.z = f2bf_rn(f2 - __uint_as_float((unsigned)hb.z << 16));
        lb.w = f2bf_rn(f3 - __uint_as_float((unsigned)hb.w << 16));
      }
      // half=0 threads own k 0..15 (elem 0-3 of entry), half=1 own k 16..31 (elem 4-7)
      *(ushort4*)&Ah[c][r][half * 4] = ha;
      *(ushort4*)&Al[c][r][half * 4] = la;
      *(ushort4*)&Bh[c][r][half * 4] = hb;
      *(ushort4*)&Bl[c][r][half * 4] = lb;
    }
    __syncthreads();
    bf16x8 bhf[4], blf[4];
#pragma unroll
    for (int j = 0; j < 4; ++j) {
      bhf[j] = *(const bf16x8*)&Bh[qp][wc * 64 + j * 16 + fr][0];
      blf[j] = *(const bf16x8*)&Bl[qp][wc * 64 + j * 16 + fr][0];
    }
#pragma unroll
    for (int i = 0; i < 4; ++i) {
      bf16x8 ahf = *(const bf16x8*)&Ah[qp][wr * 64 + i * 16 + fr][0];
      bf16x8 alf = *(const bf16x8*)&Al[qp][wr * 64 + i * 16 + fr][0];
#pragma unroll
      for (int j = 0; j < 4; ++j) {
        acc[i][j] = __builtin_amdgcn_mfma_f32_16x16x32_bf16(ahf, bhf[j], acc[i][j], 0, 0, 0);
        acc[i][j] = __builtin_amdgcn_mfma_f32_16x16x32_bf16(ahf, blf[j], acc[i][j], 0, 0, 0);
        acc[i][j] = __builtin_amdgcn_mfma_f32_16x16x32_bf16(alf, bhf[j], acc[i][j], 0, 0, 0);
      }
    }
  }
  // C write: row = (lane>>4)*4 + reg, col = lane&15 (m89-verified layout)
#pragma unroll
  for (int i = 0; i < 4; ++i) {
    int row0 = bm + wr * 64 + i * 16 + qp * 4;
#pragma unroll
    for (int j = 0; j < 4; ++j) {
      int col = bn + wc * 64 + j * 16 + fr;
#pragma unroll
      for (int t = 0; t < 4; ++t) {
        int row = row0 + t;
        if (row < M) Cc[(size_t)row * No + col] = acc[i][j][t];
      }
    }
  }
}

// ============ MLP layer 1: hid = relu(A @ B^T + bias) (fp32, K=64) ============
#define BM 128
#define BN 128
#define BK 16
#define LDP (BM + 4)
__global__ __launch_bounds__(256) void gemm_bias_relu(const float* __restrict__ A,
                                                      const float* __restrict__ B,
                                                      const float* __restrict__ bias,
                                                      float* __restrict__ Cc,
                                                      int M, int K, int No) {
  __shared__ float As[BK][LDP];
  __shared__ float Bs[BK][LDP];
  const int bm = blockIdx.x * BM;
  const int bn = blockIdx.y * BN;
  const int tid = threadIdx.x;
  const int tx = tid & 15, ty = tid >> 4;
  const int lrow = tid >> 1;
  const int lk   = (tid & 1) << 3;
  const bool arow_ok = (bm + lrow < M);
  const bool brow_ok = (bn + lrow < No);
  const float* aptr = A + (size_t)(bm + lrow) * K + lk;
  const float* bptr = B + (size_t)(bn + lrow) * K + lk;
  float acc[8][8] = {};
  for (int k0 = 0; k0 < K; k0 += BK) {
    float4 a0 = make_float4(0.f, 0.f, 0.f, 0.f), a1 = a0, b0 = a0, b1 = a0;
    if (arow_ok) {
      const float* ap = aptr + k0;
      a0 = *(const float4*)ap;
      a1 = *(const float4*)(ap + 4);
    }
    if (brow_ok) {
      const float* bp = bptr + k0;
      b0 = *(const float4*)bp;
      b1 = *(const float4*)(bp + 4);
    }
    __syncthreads();
    As[lk + 0][lrow] = a0.x; As[lk + 1][lrow] = a0.y; As[lk + 2][lrow] = a0.z; As[lk + 3][lrow] = a0.w;
    As[lk + 4][lrow] = a1.x; As[lk + 5][lrow] = a1.y; As[lk + 6][lrow] = a1.z; As[lk + 7][lrow] = a1.w;
    Bs[lk + 0][lrow] = b0.x; Bs[lk + 1][lrow] = b0.y; Bs[lk + 2][lrow] = b0.z; Bs[lk + 3][lrow] = b0.w;
    Bs[lk + 4][lrow] = b1.x; Bs[lk + 5][lrow] = b1.y; Bs[lk + 6][lrow] = b1.z; Bs[lk + 7][lrow] = b1.w;
    __syncthreads();
#pragma unroll
    for (int kk = 0; kk < BK; ++kk) {
      float a[8];
      *(float4*)&a[0] = *(const float4*)&As[kk][ty * 8];
      *(float4*)&a[4] = *(const float4*)&As[kk][ty * 8 + 4];
      {
        float4 bv = *(const float4*)&Bs[kk][tx * 4];
#pragma unroll
        for (int i = 0; i < 8; ++i) {
          acc[i][0] += a[i] * bv.x; acc[i][1] += a[i] * bv.y;
          acc[i][2] += a[i] * bv.z; acc[i][3] += a[i] * bv.w;
        }
      }
      {
        float4 bv = *(const float4*)&Bs[kk][64 + tx * 4];
#pragma unroll
        for (int i = 0; i < 8; ++i) {
          acc[i][4] += a[i] * bv.x; acc[i][5] += a[i] * bv.y;
          acc[i][6] += a[i] * bv.z; acc[i][7] += a[i] * bv.w;
        }
      }
    }
  }
#pragma unroll
  for (int i = 0; i < 8; ++i) {
    int r = bm + ty * 8 + i;
    if (r < M) {
      float* cp = Cc + (size_t)r * No + bn;
#pragma unroll
      for (int j = 0; j < 4; ++j) {
        int col = tx * 4 + j;
        cp[col] = fmaxf(acc[i][j] + bias[bn + col], 0.f);
      }
#pragma unroll
      for (int j = 0; j < 4; ++j) {
        int col = 64 + tx * 4 + j;
        cp[col] = fmaxf(acc[i][4 + j] + bias[bn + col], 0.f);
      }
    }
  }
}

// ============ MLP layer 2: out[n,o] = <hid[n,:], Wl2[o,:]> + bl2[o] ============
__global__ __launch_bounds__(256) void head_out(const float* __restrict__ hid,
                                                const float* __restrict__ Wl2,
                                                const float* __restrict__ bl2,
                                                float* __restrict__ out, int n_nodes) {
  int t = blockIdx.x * 256 + threadIdx.x;
  int n = t >> 4, o = t & 15;
  if (n >= n_nodes) return;
  const float4* hp = (const float4*)(hid + (size_t)n * 128);
  const float4* wp = (const float4*)(Wl2 + (size_t)o * 128);
  float acc = bl2[o];
#pragma unroll
  for (int k = 0; k < 32; ++k) {
    float4 hv = hp[k], wv = wp[k];
    acc += hv.x * wv.x + hv.y * wv.y + hv.z * wv.z + hv.w * wv.w;
  }
  out[(size_t)n * 16 + o] = acc;
}

// =========== exact (fp64) attention-score folds, both convs ===========
__global__ __launch_bounds__(256) void fold_att1(const float* __restrict__ W1,
                                                 const float* __restrict__ att_s,
                                                 const float* __restrict__ att_d,
                                                 double* __restrict__ wt) {
  int t = blockIdx.x * 256 + threadIdx.x;   // t = h*HC + k, total 1024
  if (t >= H_ * HC) return;
  int h = t >> 8;
  int k = t & (HC - 1);
  double s = 0.0, d = 0.0;
#pragma unroll 4
  for (int c = 0; c < C_; ++c) {
    double w = (double)W1[(size_t)(h * C_ + c) * HC + k];
    s += w * (double)att_s[h * C_ + c];
    d += w * (double)att_d[h * C_ + c];
  }
  wt[(size_t)(2 * h + 0) * HC + k] = s;
  wt[(size_t)(2 * h + 1) * HC + k] = d;
}

__global__ __launch_bounds__(256) void fold_att2(const float* __restrict__ W2,
                                                 const float* __restrict__ att_s,
                                                 const float* __restrict__ att_d,
                                                 double* __restrict__ u_s,
                                                 double* __restrict__ u_d) {
  int t = blockIdx.x * 256 + threadIdx.x;
  if (t >= H_ * HC) return;
  int h = t >> 8;
  int k = t & (HC - 1);
  double s = 0.0, d = 0.0;
#pragma unroll 4
  for (int c = 0; c < C_; ++c) {
    double w = (double)W2[(size_t)(h * C_ + c) * HC + k];
    s += w * (double)att_s[h * C_ + c];
    d += w * (double)att_d[h * C_ + c];
  }
  u_s[t] = s;
  u_d[t] = d;
}

// vv -> wt rows 8..39, plus cst[8] (cst[0..3]=s, cst[4..7]=d)
__global__ __launch_bounds__(256) void fold_vv(const float* __restrict__ W1,
                                               const double* __restrict__ u2s,
                                               const double* __restrict__ u2d,
                                               const float* __restrict__ b1,
                                               double* __restrict__ wt,
                                               double* __restrict__ cst) {
  int t = blockIdx.x * 256 + threadIdx.x;
  if (t < 8192) {
    int type = t >> 12;          // 0=s, 1=d
    int rem = t & 4095;          // hh*256 + j
    int j = rem & 255;
    int hh = rem >> 8;           // h*4 + h'
    int h = hh >> 2, hp = hh & 3;
    const double* u2 = type ? u2d : u2s;
    double acc = 0.0;
#pragma unroll 4
    for (int c = 0; c < C_; ++c)
      acc += (double)W1[(size_t)(h * C_ + c) * HC + j] * u2[hp * HC + h * C_ + c];
    wt[(size_t)(8 + type * 16 + hh) * HC + j] = acc;
  } else if (t < 8200) {
    int q = t - 8192;            // 0..7
    const double* u2 = (q >> 2) ? u2d : u2s;
    int hp = q & 3;
    double acc = 0.0;
    for (int k = 0; k < HC; ++k) acc += (double)b1[k] * u2[hp * HC + k];
    cst[q] = acc;
  }
}

// ====== score GEMM — C[N,40] = x[N,256] . wt[40,256]^T, fp64 acc ======
#define SNB 128
#define SKB 32
__global__ __launch_bounds__(256) void scores_gemm(const float* __restrict__ x,
                                                   const double* __restrict__ wt,
                                                   double* __restrict__ as1,
                                                   double* __restrict__ ad1,
                                                   double* __restrict__ zz, int n_nodes) {
  __shared__ float  Xs[SNB][SKB + 1];
  __shared__ double Ws[40][SKB + 1];
  const int tid = threadIdx.x;
  const int n0 = blockIdx.x * SNB;
  const int g = tid & 3;
  const int p = tid >> 2;
  double acc0[10] = {}, acc1[10] = {};
  for (int k0 = 0; k0 < HC; k0 += SKB) {
    __syncthreads();
    {
      int row = tid >> 1;
      int colb = (tid & 1) * 16;
      float* d = &Xs[row][colb];
      int n = n0 + row;
      if (n < n_nodes) {
        const float* xp = x + (size_t)n * HC + k0 + colb;
        float4 v0 = *(const float4*)(xp);
        float4 v1 = *(const float4*)(xp + 4);
        float4 v2 = *(const float4*)(xp + 8);
        float4 v3 = *(const float4*)(xp + 12);
        d[0] = v0.x;  d[1] = v0.y;  d[2] = v0.z;  d[3] = v0.w;
        d[4] = v1.x;  d[5] = v1.y;  d[6] = v1.z;  d[7] = v1.w;
        d[8] = v2.x;  d[9] = v2.y;  d[10] = v2.z; d[11] = v2.w;
        d[12] = v3.x; d[13] = v3.y; d[14] = v3.z; d[15] = v3.w;
      } else {
#pragma unroll
        for (int j = 0; j < 16; ++j) d[j] = 0.f;
      }
    }
#pragma unroll
    for (int q = 0; q < 5; ++q) {
      int idx = tid + q * 256;
      int row = idx >> 5, col = idx & 31;
      Ws[row][col] = wt[(size_t)row * HC + k0 + col];
    }
    __syncthreads();
#pragma unroll
    for (int kk = 0; kk < SKB; ++kk) {
      double xv0 = (double)Xs[2 * p][kk];
      double xv1 = (double)Xs[2 * p + 1][kk];
#pragma unroll
      for (int ci = 0; ci < 10; ++ci) {
        double w = Ws[g * 10 + ci][kk];
        acc0[ci] += xv0 * w;
        acc1[ci] += xv1 * w;
      }
    }
  }
  const int na = n0 + 2 * p;
  const int nb = na + 1;
  if (na < n_nodes) {
#pragma unroll
    for (int ci = 0; ci < 10; ++ci) {
      int c = g * 10 + ci;
      double v = acc0[ci];
      if (c < 8)       ((c & 1) ? ad1 : as1)[na * H_ + (c >> 1)] = v;
      else if (c < 24) { int hh = c - 8;  zz[((size_t)na * H_ + (hh >> 2)) * 8 + (hh & 3)] = v; }
      else             { int hh = c - 24; zz[((size_t)na * H_ + (hh >> 2)) * 8 + 4 + (hh & 3)] = v; }
    }
  }
  if (nb < n_nodes) {
#pragma unroll
    for (int ci = 0; ci < 10; ++ci) {
      int c = g * 10 + ci;
      double v = acc1[ci];
      if (c < 8)       ((c & 1) ? ad1 : as1)[nb * H_ + (c >> 1)] = v;
      else if (c < 24) { int hh = c - 8;  zz[((size_t)nb * H_ + (hh >> 2)) * 8 + (hh & 3)] = v; }
      else             { int hh = c - 24; zz[((size_t)nb * H_ + (hh >> 2)) * 8 + 4 + (hh & 3)] = v; }
    }
  }
}

// ====================== CSR build: multi-block scan ======================
__global__ void count_edges(const int* __restrict__ dst, int E_, int* __restrict__ counts) {
  int e = blockIdx.x * blockDim.x + threadIdx.x;
  if (e < E_) atomicAdd(&counts[dst[e]], 1);
}

#define SCB 256
__global__ __launch_bounds__(SCB) void scan_phase1(const int* __restrict__ counts, int n,
                                                   int* __restrict__ row_start,
                                                   int* __restrict__ bsum) {
  __shared__ int sh[SCB];
  int b = blockIdx.x, t = threadIdx.x;
  int idx = b * SCB + t;
  int v = (idx < n) ? counts[idx] : 0;
  sh[t] = v;
  __syncthreads();
  for (int off = 1; off < SCB; off <<= 1) {
    int u = (t >= off) ? sh[t - off] : 0;
    __syncthreads();
    sh[t] += u;
    __syncthreads();
  }
  if (idx < n) row_start[idx] = sh[t] - v;   // block-local exclusive
  if (t == SCB - 1) bsum[b] = sh[t];
}

__global__ __launch_bounds__(SCB) void scan_phase2(int* __restrict__ bsum, int nb) {
  __shared__ int sh[SCB];
  int t = threadIdx.x;
  int v = (t < nb) ? bsum[t] : 0;
  sh[t] = v;
  __syncthreads();
  for (int off = 1; off < SCB; off <<= 1) {
    int u = (t >= off) ? sh[t - off] : 0;
    __syncthreads();
    sh[t] += u;
    __syncthreads();
  }
  if (t < nb) bsum[t] = sh[t] - v;           // exclusive, in place
}

__global__ __launch_bounds__(SCB) void scan_phase3(int n, const int* __restrict__ bsum,
                                                   int* __restrict__ row_start,
                                                   int* __restrict__ wptr, int E_) {
  int b = blockIdx.x, t = threadIdx.x;
  int idx = b * SCB + t;
  if (idx < n) {
    int r = row_start[idx] + bsum[b];
    row_start[idx] = r;
    wptr[idx] = r;
  } else if (idx == n) {
    row_start[n] = E_;
  }
}

__global__ void scatter_edges(const int* __restrict__ src, const int* __restrict__ dst, int E_,
                              int* __restrict__ wptr, int* __restrict__ csr_src) {
  int e = blockIdx.x * blockDim.x + threadIdx.x;
  if (e < E_) {
    int p = atomicAdd(&wptr[dst[e]], 1);
    csr_src[p] = src[e];
  }
}

// only rare big nodes (deg>32) take an atomic
__global__ void bin_big(const int* __restrict__ row_start, int n_nodes,
                        int* __restrict__ list64, int* __restrict__ cnt) {
  int n = blockIdx.x * blockDim.x + threadIdx.x;
  if (n >= n_nodes) return;
  int deg = row_start[n + 1] - row_start[n];
  if (deg > 32) { int p = atomicAdd(&cnt[1], 1); list64[p] = n; }
}

// ====================== top-K select (u64-key bitonic) ======================
__device__ inline unsigned long long shfl_xor_u64(unsigned long long x, int m) {
  int lo = __shfl_xor((int)(x & 0xffffffffull), m);
  int hi = __shfl_xor((int)(x >> 32), m);
  return ((unsigned long long)(unsigned int)hi << 32) | (unsigned int)lo;
}
__device__ inline unsigned long long mono_key(double v) {
  unsigned long long u = (unsigned long long)__double_as_longlong(v);
  return (u & 0x8000000000000000ull) ? ~u : (u | 0x8000000000000000ull);
}
__device__ inline double mono_val(unsigned long long k) {
  unsigned long long u = (k & 0x8000000000000000ull) ? (k ^ 0x8000000000000000ull) : ~k;
  return __longlong_as_double((long long)u);
}

// iterates node ids directly; skips deg>32 (handled by select64)
__global__ __launch_bounds__(256) void select32(const double* __restrict__ as_,
                                                const double* __restrict__ ad_,
                                                const int* __restrict__ row_start,
                                                const int* __restrict__ csr_src,
                                                int n_nodes,
                                                int* __restrict__ ksrc,
                                                float* __restrict__ kw,
                                                double* __restrict__ kw64) {
  const int slot = threadIdx.x & 31;           // position within 32-group
  const int grp  = threadIdx.x >> 5;           // 0..7
  const int nl   = grp >> 2;                   // node-local 0..1
  const int h    = grp & 3;
  const int lane = threadIdx.x & 63;           // absolute lane in wave
  const int gbase = lane & 32;                 // group base within wave
  for (int base = blockIdx.x * 2; base < n_nodes; base += gridDim.x * 2) {
    int n = base + nl;
    bool active = (n < n_nodes);
    int nn = active ? n : 0;
    int rs = row_start[nn];
    int deg = active ? (row_start[nn + 1] - rs) : 0;
    if (deg > 32) { active = false; deg = 0; }   // big nodes -> select64
    double adv = ad_[nn * H_ + h];
    int kcount = deg < KTOP ? deg : KTOP;

    unsigned long long key; int sv;
    if (slot < deg) {
      int s = csr_src[rs + slot];
      double a = as_[s * H_ + h] + adv;
      double v = (a >= 0.0) ? a : (double)NEG_SLOPE * a;
      key = (mono_key(v) & ~31ull) | (unsigned long long)(31 - slot);
      sv = s;
    } else {
      key = (mono_key(-INFINITY) & ~31ull) | (unsigned long long)(31 - slot);
      sv = -1;
    }
#pragma unroll
    for (int kk = 2; kk <= 32; kk <<= 1) {
#pragma unroll
      for (int j = kk >> 1; j > 0; j >>= 1) {
        unsigned long long ok = shfl_xor_u64(key, j);
        bool dirDesc = ((slot & kk) == 0);
        bool lower   = ((slot & j) == 0);
        bool mineFirst = key > ok;
        if ((dirDesc == lower) ? !mineFirst : mineFirst) key = ok;
      }
    }
    int wslot = 31 - (int)(key & 31ull);
    int sid = __shfl(sv, gbase + wslot);
    double vrec = mono_val(key & ~31ull);
    double m = __shfl(vrec, gbase);            // slot 0 of group = max
    double ex = (slot < kcount) ? exp(vrec - m) : 0.0;
    double den = ex;
#pragma unroll
    for (int off = 16; off >= 1; off >>= 1) den += __shfl_xor(den, off);
    double inv = (kcount > 0) ? 1.0 / den : 0.0;
    double wgt = ex * inv;                     // exactly 0.0 beyond kcount

    if (active && slot < KTOP) {
      size_t u = ((size_t)n * H_ + h) * KTOP + slot;
      ksrc[u] = (sid >= 0) ? sid : 0;
      kw[u] = (float)wgt;
      if (kw64) kw64[u] = wgt;
    }
  }
}

__global__ __launch_bounds__(256) void select64(const double* __restrict__ as_,
                                                const double* __restrict__ ad_,
                                                const int* __restrict__ row_start,
                                                const int* __restrict__ csr_src,
                                                const int* __restrict__ list,
                                                const int* __restrict__ cnt,
                                                int* __restrict__ ksrc,
                                                float* __restrict__ kw,
                                                double* __restrict__ kw64) {
  __shared__ int    f_src[H_][16];
  __shared__ double f_w[H_][16];
  const int c = cnt[1];
  int h = threadIdx.x >> 6;
  int lane = threadIdx.x & 63;
  for (int idx = blockIdx.x; idx < c; idx += gridDim.x) {
    int n = list[idx];
    int rs = row_start[n];
    int deg = row_start[n + 1] - rs;
    if (deg > 256) deg = 256;   // safety clamp
    double adv = ad_[n * H_ + h];
    int kcount = deg < KTOP ? deg : KTOP;

    double vsel; int sid;
    if (deg <= 64) {
      unsigned long long key; int sv;
      if (lane < deg) {
        int s = csr_src[rs + lane];
        double a = as_[s * H_ + h] + adv;
        double v = (a >= 0.0) ? a : (double)NEG_SLOPE * a;
        key = (mono_key(v) & ~63ull) | (unsigned long long)(63 - lane);
        sv = s;
      } else {
        key = (mono_key(-INFINITY) & ~63ull) | (unsigned long long)(63 - lane);
        sv = -1;
      }
#pragma unroll
      for (int kk = 2; kk <= 64; kk <<= 1) {
#pragma unroll
        for (int j = kk >> 1; j > 0; j >>= 1) {
          unsigned long long ok = shfl_xor_u64(key, j);
          bool dirDesc = ((lane & kk) == 0);
          bool lower   = ((lane & j) == 0);
          bool mineFirst = key > ok;
          if ((dirDesc == lower) ? !mineFirst : mineFirst) key = ok;
        }
      }
      int wslot = 63 - (int)(key & 63ull);
      sid = __shfl(sv, wslot);
      vsel = mono_val(key & ~63ull);
    } else {
      double av[4]; int svr[4];
#pragma unroll
      for (int q = 0; q < 4; ++q) {
        int id2 = lane + (q << 6);
        if (id2 < deg) {
          int s = csr_src[rs + id2];
          double a = as_[s * H_ + h] + adv;
          av[q] = (a >= 0.0) ? a : (double)NEG_SLOPE * a;
          svr[q] = s;
        } else {
          av[q] = -INFINITY; svr[q] = -1;
        }
      }
      for (int it = 0; it < kcount; ++it) {
        double best = av[0]; int bq = 0;
#pragma unroll
        for (int q = 1; q < 4; ++q)
          if (av[q] > best) { best = av[q]; bq = q; }
        double bv = best; int bl = lane;
#pragma unroll
        for (int off = 32; off >= 1; off >>= 1) {
          double ov = __shfl_down(bv, off);
          int    ol = __shfl_down(bl, off);
          if (ov > bv || (ov == bv && ol < bl)) { bv = ov; bl = ol; }
        }
        bl = __shfl(bl, 0);
        if (lane == bl) {
          f_src[h][it] = svr[bq];
          f_w[h][it] = best;
          av[bq] = -INFINITY;
        }
      }
      vsel = (lane < kcount) ? f_w[h][lane] : -INFINITY;
      sid  = (lane < kcount) ? f_src[h][lane] : -1;
    }

    double m = __shfl(vsel, 0);
    double ex = (lane < kcount) ? exp(vsel - m) : 0.0;
    double den = ex;
#pragma unroll
    for (int off = 32; off >= 1; off >>= 1) den += __shfl_xor(den, off);
    double inv = (kcount > 0) ? 1.0 / den : 0.0;
    double wgt = ex * inv;

    if (lane < KTOP) {
      size_t u = ((size_t)n * H_ + h) * KTOP + lane;
      ksrc[u] = (sid >= 0) ? sid : 0;
      kw[u] = (float)wgt;
      if (kw64) kw64[u] = wgt;
    }
  }
}

// ====================== conv2 scores ======================
__global__ __launch_bounds__(256) void conv2_scores(const int* __restrict__ ksrc,
                                                    const double* __restrict__ kw64,
                                                    const double* __restrict__ zz,
                                                    const double* __restrict__ cst,
                                                    double* __restrict__ as2,
                                                    double* __restrict__ ad2, int n_nodes) {
  int n = (blockIdx.x * 256 + threadIdx.x) >> 6;
  int lane = threadIdx.x & 63;
  if (n >= n_nodes) return;
  int p = lane >> 3, j = lane & 7;
  const int*    sp = ksrc + (size_t)n * H_ * KTOP;
  const double* wp = kw64 + (size_t)n * H_ * KTOP;
  double acc = 0.0;
#pragma unroll
  for (int t = 0; t < 5; ++t) {
    int q = j + t * 8;                 // 0..39
    int h = q / KTOP;
    double w = wp[q];
    int s = sp[q];
    acc += w * zz[((size_t)s * H_ + h) * 8 + p];
  }
#pragma unroll
  for (int off = 4; off >= 1; off >>= 1) acc += __shfl_xor(acc, off);
  if (j == 0) {
    double vo = acc + cst[p];
    if (p < 4) as2[n * H_ + p] = vo;
    else       ad2[n * H_ + (p - 4)] = vo;
  }
}

// ====================== gather/aggregate (one node per wave) ======================
template <int CONCAT>
__global__ __launch_bounds__(256) void gather_agg(const float* __restrict__ xl,
                                                  const int* __restrict__ ksrc,
                                                  const float* __restrict__ kw,
                                                  const float* __restrict__ bias,
                                                  float* __restrict__ out, int n_nodes) {
  int n = (blockIdx.x * 256 + threadIdx.x) >> 6;   // one node per wave
  int lane = threadIdx.x & 63;
  if (n >= n_nodes) return;
  const int*   sp = ksrc + (size_t)n * H_ * KTOP;
  const float* wp = kw   + (size_t)n * H_ * KTOP;
  int ss[H_ * KTOP];
#pragma unroll
  for (int k = 0; k < H_ * KTOP; ++k) ss[k] = sp[k];
  float xv[H_ * KTOP];
#pragma unroll
  for (int h = 0; h < H_; ++h)
#pragma unroll
    for (int i = 0; i < KTOP; ++i)
      xv[h * KTOP + i] = xl[(size_t)ss[h * KTOP + i] * HC + h * C_ + lane];
  float accs[H_];
#pragma unroll
  for (int h = 0; h < H_; ++h) {
    float a = 0.f;
#pragma unroll
    for (int i = 0; i < KTOP; ++i) a += wp[h * KTOP + i] * xv[h * KTOP + i];
    accs[h] = a;
  }
  if (CONCAT) {
#pragma unroll
    for (int h = 0; h < H_; ++h)
      out[(size_t)n * HC + h * C_ + lane] = accs[h] + bias[h * C_ + lane];
  } else {
    out[(size_t)n * C_ + lane] =
        0.25f * (accs[0] + accs[1] + accs[2] + accs[3]) + bias[lane];
  }
}

// ============================== launcher ==============================
extern "C" void kernel_launch(void* const* d_in, const int* in_sizes, int n_in,
                              void* d_out, int out_size, void* d_ws, size_t ws_size,
                              hipStream_t stream) {
  const float* x      = (const float*)d_in[0];
  const float* W1     = (const float*)d_in[1];
  const float* att_s1 = (const float*)d_in[2];
  const float* att_d1 = (const float*)d_in[3];
  const float* b1     = (const float*)d_in[4];
  const float* W2     = (const float*)d_in[5];
  const float* att_s2 = (const float*)d_in[6];
  const float* att_d2 = (const float*)d_in[7];
  const float* b2     = (const float*)d_in[8];
  const float* Wl1    = (const float*)d_in[9];
  const float* bl1    = (const float*)d_in[10];
  const float* Wl2    = (const float*)d_in[11];
  const float* bl2    = (const float*)d_in[12];
  const int*   eidx   = (const int*)d_in[13];

  const int N_ = in_sizes[0] / F_IN;     // 50000
  const int E_ = in_sizes[13] / 2;       // 800000
  const int* e_src = eidx;
  const int* e_dst = eidx + E_;

  // workspace layout
  char* base = (char*)d_ws;
  size_t off = 0;
  auto alloc = [&](size_t bytes) -> char* {
    char* p = base + off;
    off = (off + bytes + 255) & ~(size_t)255;
    return p;
  };
  float*  xl        = (float*)alloc((size_t)N_ * HC * 4);
  float*  hbuf      = (float*)alloc((size_t)N_ * HC * 4);   // h1; later h2 (N*64)
  double* as1       = (double*)alloc((size_t)N_ * H_ * 8);
  double* ad1       = (double*)alloc((size_t)N_ * H_ * 8);
  double* as2       = (double*)alloc((size_t)N_ * H_ * 8);
  double* ad2       = (double*)alloc((size_t)N_ * H_ * 8);
  double* zz        = (double*)alloc((size_t)N_ * H_ * 8 * 8);  // [s][h][8] packed
  double* wt        = (double*)alloc((size_t)40 * HC * 8);
  double* u2s       = (double*)alloc((size_t)H_ * HC * 8);
  double* u2d       = (double*)alloc((size_t)H_ * HC * 8);
  double* cst       = (double*)alloc((size_t)8 * 8);
  int*    ksrc1     = (int*)alloc((size_t)N_ * H_ * KTOP * 4);
  float*  kw1       = (float*)alloc((size_t)N_ * H_ * KTOP * 4);
  double* kw64_1    = (double*)alloc((size_t)N_ * H_ * KTOP * 8);
  int*    ksrc2     = (int*)alloc((size_t)N_ * H_ * KTOP * 4);
  float*  kw2       = (float*)alloc((size_t)N_ * H_ * KTOP * 4);
  int*    list64    = (int*)alloc((size_t)N_ * 4);
  int*    cnt       = (int*)alloc((size_t)8 * 4);
  int*    bsum      = (int*)alloc((size_t)SCB * 4);
  int* counts       = (int*)alloc((size_t)N_ * 4);
  int* row_start    = (int*)alloc((size_t)(N_ + 1) * 4);
  int* wptr         = (int*)alloc((size_t)N_ * 4);
  int* csr_src      = (int*)alloc((size_t)E_ * 4);
  (void)ws_size;
  float* hidbuf  = xl;   // xl dead after gather_agg<0>; N*128 <= N*256 slot

  const int eb = (E_ + 255) / 256;
  const int nb = (N_ + 255) / 256;
  const int sb = (N_ + 1 + SCB - 1) / SCB;

  // ---- CSR build (multi-block scan) + big-node list ----
  hipMemsetAsync(counts, 0, (size_t)N_ * 4, stream);
  hipMemsetAsync(cnt, 0, 32, stream);
  count_edges<<<eb, 256, 0, stream>>>(e_dst, E_, counts);
  scan_phase1<<<sb, SCB, 0, stream>>>(counts, N_, row_start, bsum);
  scan_phase2<<<1, SCB, 0, stream>>>(bsum, sb);
  scan_phase3<<<sb, SCB, 0, stream>>>(N_, bsum, row_start, wptr, E_);
  scatter_edges<<<eb, 256, 0, stream>>>(e_src, e_dst, E_, wptr, csr_src);
  bin_big<<<nb, 256, 0, stream>>>(row_start, N_, list64, cnt);

  // ---- fp64 score folds + score GEMM ----
  fold_att1<<<(H_ * HC + 255) / 256, 256, 0, stream>>>(W1, att_s1, att_d1, wt);
  fold_att2<<<(H_ * HC + 255) / 256, 256, 0, stream>>>(W2, att_s2, att_d2, u2s, u2d);
  fold_vv<<<(8200 + 255) / 256, 256, 0, stream>>>(W1, u2s, u2d, b1, wt, cst);
  scores_gemm<<<(N_ + SNB - 1) / SNB, 256, 0, stream>>>(x, wt, as1, ad1, zz, N_);

  // ---- conv1 value GEMM (bf16x3 MFMA) ----
  dim3 ggrid((N_ + GM - 1) / GM, HC / GN);
  gemm_nt_mfma<<<ggrid, 256, 0, stream>>>(x, W1, xl, N_, F_IN, HC);

  // ---- selection conv1 (binned) + exact conv2 scores ----
  select32<<<6250, 256, 0, stream>>>(as1, ad1, row_start, csr_src, N_, ksrc1, kw1, kw64_1);
  select64<<<1024, 256, 0, stream>>>(as1, ad1, row_start, csr_src, list64, cnt,
                                     ksrc1, kw1, kw64_1);
  conv2_scores<<<(N_ + 3) / 4, 256, 0, stream>>>(ksrc1, kw64_1, zz, cst, as2, ad2, N_);

  // ---- selection conv2 (binned) ----
  select32<<<6250, 256, 0, stream>>>(as2, ad2, row_start, csr_src, N_, ksrc2, kw2, nullptr);
  select64<<<1024, 256, 0, stream>>>(as2, ad2, row_start, csr_src, list64, cnt,
                                     ksrc2, kw2, nullptr);

  const int agg_blocks = (N_ + 3) / 4;   // one node per 64-lane wave

  // ---- conv1 aggregate ----
  gather_agg<1><<<agg_blocks, 256, 0, stream>>>(xl, ksrc1, kw1, b1, hbuf, N_);

  // ---- conv2 ----
  gemm_nt_mfma<<<ggrid, 256, 0, stream>>>(hbuf, W2, xl, N_, HC, HC);
  gather_agg<0><<<agg_blocks, 256, 0, stream>>>(xl, ksrc2, kw2, b2, hbuf, N_);

  // ---- MLP head ----
  dim3 hgrid((N_ + BM - 1) / BM, 1);
  gemm_bias_relu<<<hgrid, 256, 0, stream>>>(hbuf, Wl1, bl1, hidbuf, N_, C_, 128);
  head_out<<<(N_ * 16 + 255) / 256, 256, 0, stream>>>(hidbuf, Wl2, bl2, (float*)d_out, N_);
}

// Round 12
// 667.204 us; speedup vs baseline: 2.3141x; 1.0744x over previous
//
#include <hip/hip_runtime.h>
#include <math.h>

#define F_IN 256
#define HC   256   // H*C
#define H_   4
#define C_   64
#define KTOP 10
#define NEG_SLOPE 0.2f

typedef __attribute__((ext_vector_type(8))) short bf16x8;
typedef __attribute__((ext_vector_type(4))) float f32x4;

__device__ inline unsigned short f2h(float f) {
  _Float16 h = (_Float16)f;          // v_cvt_f16_f32 (RN)
  return *(unsigned short*)&h;
}
__device__ inline float h2f(unsigned short u) {
  _Float16 h = *(_Float16*)&u;
  return (float)h;                   // v_cvt_f32_f16
}

// ============ bf16x3 split-MFMA GEMM: Ch[M,No](fp16) = A[M,K] @ B[No,K]^T ============
// R22: output fp16-only. The GEMM result (xl) is consumed ONLY by gather_agg
// (selection exactness is carried by the fp64 score path; conv2's GEMM reads
// the fp32 aggregation output hbuf). fp16 value quantization = 2^-11 relative,
// and halves GEMM write traffic AND gather fetch traffic.
#define GM 128
#define GN 128
#define GK 32
__device__ inline unsigned short f2bf_rn(float f) {
  unsigned u = __float_as_uint(f);
  unsigned r = u + 0x7FFFu + ((u >> 16) & 1u);
  return (unsigned short)(r >> 16);
}
__global__ __launch_bounds__(256) void gemm_nt_mfma(const float* __restrict__ A,
                                                    const float* __restrict__ B,
                                                    unsigned short* __restrict__ Ch,
                                                    int M, int K, int No) {
  __shared__ unsigned short Ah[4][128][8], Al[4][128][8];
  __shared__ unsigned short Bh[4][128][8], Bl[4][128][8];
  const int tid = threadIdx.x;
  const int bm = blockIdx.x * GM, bn = blockIdx.y * GN;
  const int r = tid >> 1, half = tid & 1;          // staging: row 0..127, k-half
  const int wid = tid >> 6, lane = tid & 63;
  const int wr = wid >> 1, wc = wid & 1;           // wave -> 64x64 quadrant
  const int qp = lane >> 4, fr = lane & 15;
  const bool arow_ok = (bm + r < M);
  const float* ap = A + (size_t)(bm + r) * K + half * 16;
  const float* bp = B + (size_t)(bn + r) * K + half * 16;
  f32x4 acc[4][4];
#pragma unroll
  for (int i = 0; i < 4; ++i)
#pragma unroll
    for (int j = 0; j < 4; ++j) acc[i][j] = (f32x4){0.f, 0.f, 0.f, 0.f};

  for (int k0 = 0; k0 < K; k0 += GK) {
    float va[16], vb[16];
    if (arow_ok) {
      *(float4*)&va[0]  = *(const float4*)(ap + k0);
      *(float4*)&va[4]  = *(const float4*)(ap + k0 + 4);
      *(float4*)&va[8]  = *(const float4*)(ap + k0 + 8);
      *(float4*)&va[12] = *(const float4*)(ap + k0 + 12);
    } else {
#pragma unroll
      for (int j = 0; j < 16; ++j) va[j] = 0.f;
    }
    *(float4*)&vb[0]  = *(const float4*)(bp + k0);
    *(float4*)&vb[4]  = *(const float4*)(bp + k0 + 4);
    *(float4*)&vb[8]  = *(const float4*)(bp + k0 + 8);
    *(float4*)&vb[12] = *(const float4*)(bp + k0 + 12);
    __syncthreads();   // previous tile's frag reads done
#pragma unroll
    for (int c = 0; c < 4; ++c) {
      ushort4 ha, la, hb, lb;
      {
        float f0 = va[c * 4 + 0], f1 = va[c * 4 + 1], f2 = va[c * 4 + 2], f3 = va[c * 4 + 3];
        ha.x = f2bf_rn(f0); ha.y = f2bf_rn(f1); ha.z = f2bf_rn(f2); ha.w = f2bf_rn(f3);
        la.x = f2bf_rn(f0 - __uint_as_float((unsigned)ha.x << 16));
        la.y = f2bf_rn(f1 - __uint_as_float((unsigned)ha.y << 16));
        la.z = f2bf_rn(f2 - __uint_as_float((unsigned)ha.z << 16));
        la.w = f2bf_rn(f3 - __uint_as_float((unsigned)ha.w << 16));
      }
      {
        float f0 = vb[c * 4 + 0], f1 = vb[c * 4 + 1], f2 = vb[c * 4 + 2], f3 = vb[c * 4 + 3];
        hb.x = f2bf_rn(f0); hb.y = f2bf_rn(f1); hb.z = f2bf_rn(f2); hb.w = f2bf_rn(f3);
        lb.x = f2bf_rn(f0 - __uint_as_float((unsigned)hb.x << 16));
        lb.y = f2bf_rn(f1 - __uint_as_float((unsigned)hb.y << 16));
        lb.z = f2bf_rn(f2 - __uint_as_float((unsigned)hb.z << 16));
        lb.w = f2bf_rn(f3 - __uint_as_float((unsigned)hb.w << 16));
      }
      *(ushort4*)&Ah[c][r][half * 4] = ha;
      *(ushort4*)&Al[c][r][half * 4] = la;
      *(ushort4*)&Bh[c][r][half * 4] = hb;
      *(ushort4*)&Bl[c][r][half * 4] = lb;
    }
    __syncthreads();
    bf16x8 bhf[4], blf[4];
#pragma unroll
    for (int j = 0; j < 4; ++j) {
      bhf[j] = *(const bf16x8*)&Bh[qp][wc * 64 + j * 16 + fr][0];
      blf[j] = *(const bf16x8*)&Bl[qp][wc * 64 + j * 16 + fr][0];
    }
#pragma unroll
    for (int i = 0; i < 4; ++i) {
      bf16x8 ahf = *(const bf16x8*)&Ah[qp][wr * 64 + i * 16 + fr][0];
      bf16x8 alf = *(const bf16x8*)&Al[qp][wr * 64 + i * 16 + fr][0];
#pragma unroll
      for (int j = 0; j < 4; ++j) {
        acc[i][j] = __builtin_amdgcn_mfma_f32_16x16x32_bf16(ahf, bhf[j], acc[i][j], 0, 0, 0);
        acc[i][j] = __builtin_amdgcn_mfma_f32_16x16x32_bf16(ahf, blf[j], acc[i][j], 0, 0, 0);
        acc[i][j] = __builtin_amdgcn_mfma_f32_16x16x32_bf16(alf, bhf[j], acc[i][j], 0, 0, 0);
      }
    }
  }
  // C write (fp16): row = (lane>>4)*4 + reg, col = lane&15 (m89-verified layout)
#pragma unroll
  for (int i = 0; i < 4; ++i) {
    int row0 = bm + wr * 64 + i * 16 + qp * 4;
#pragma unroll
    for (int j = 0; j < 4; ++j) {
      int col = bn + wc * 64 + j * 16 + fr;
#pragma unroll
      for (int t = 0; t < 4; ++t) {
        int row = row0 + t;
        if (row < M) Ch[(size_t)row * No + col] = f2h(acc[i][j][t]);
      }
    }
  }
}

// ============ MLP layer 1: hid = relu(A @ B^T + bias) (fp32, K=64) ============
#define BM 128
#define BN 128
#define BK 16
#define LDP (BM + 4)
__global__ __launch_bounds__(256) void gemm_bias_relu(const float* __restrict__ A,
                                                      const float* __restrict__ B,
                                                      const float* __restrict__ bias,
                                                      float* __restrict__ Cc,
                                                      int M, int K, int No) {
  __shared__ float As[BK][LDP];
  __shared__ float Bs[BK][LDP];
  const int bm = blockIdx.x * BM;
  const int bn = blockIdx.y * BN;
  const int tid = threadIdx.x;
  const int tx = tid & 15, ty = tid >> 4;
  const int lrow = tid >> 1;
  const int lk   = (tid & 1) << 3;
  const bool arow_ok = (bm + lrow < M);
  const bool brow_ok = (bn + lrow < No);
  const float* aptr = A + (size_t)(bm + lrow) * K + lk;
  const float* bptr = B + (size_t)(bn + lrow) * K + lk;
  float acc[8][8] = {};
  for (int k0 = 0; k0 < K; k0 += BK) {
    float4 a0 = make_float4(0.f, 0.f, 0.f, 0.f), a1 = a0, b0 = a0, b1 = a0;
    if (arow_ok) {
      const float* ap = aptr + k0;
      a0 = *(const float4*)ap;
      a1 = *(const float4*)(ap + 4);
    }
    if (brow_ok) {
      const float* bp = bptr + k0;
      b0 = *(const float4*)bp;
      b1 = *(const float4*)(bp + 4);
    }
    __syncthreads();
    As[lk + 0][lrow] = a0.x; As[lk + 1][lrow] = a0.y; As[lk + 2][lrow] = a0.z; As[lk + 3][lrow] = a0.w;
    As[lk + 4][lrow] = a1.x; As[lk + 5][lrow] = a1.y; As[lk + 6][lrow] = a1.z; As[lk + 7][lrow] = a1.w;
    Bs[lk + 0][lrow] = b0.x; Bs[lk + 1][lrow] = b0.y; Bs[lk + 2][lrow] = b0.z; Bs[lk + 3][lrow] = b0.w;
    Bs[lk + 4][lrow] = b1.x; Bs[lk + 5][lrow] = b1.y; Bs[lk + 6][lrow] = b1.z; Bs[lk + 7][lrow] = b1.w;
    __syncthreads();
#pragma unroll
    for (int kk = 0; kk < BK; ++kk) {
      float a[8];
      *(float4*)&a[0] = *(const float4*)&As[kk][ty * 8];
      *(float4*)&a[4] = *(const float4*)&As[kk][ty * 8 + 4];
      {
        float4 bv = *(const float4*)&Bs[kk][tx * 4];
#pragma unroll
        for (int i = 0; i < 8; ++i) {
          acc[i][0] += a[i] * bv.x; acc[i][1] += a[i] * bv.y;
          acc[i][2] += a[i] * bv.z; acc[i][3] += a[i] * bv.w;
        }
      }
      {
        float4 bv = *(const float4*)&Bs[kk][64 + tx * 4];
#pragma unroll
        for (int i = 0; i < 8; ++i) {
          acc[i][4] += a[i] * bv.x; acc[i][5] += a[i] * bv.y;
          acc[i][6] += a[i] * bv.z; acc[i][7] += a[i] * bv.w;
        }
      }
    }
  }
#pragma unroll
  for (int i = 0; i < 8; ++i) {
    int r = bm + ty * 8 + i;
    if (r < M) {
      float* cp = Cc + (size_t)r * No + bn;
#pragma unroll
      for (int j = 0; j < 4; ++j) {
        int col = tx * 4 + j;
        cp[col] = fmaxf(acc[i][j] + bias[bn + col], 0.f);
      }
#pragma unroll
      for (int j = 0; j < 4; ++j) {
        int col = 64 + tx * 4 + j;
        cp[col] = fmaxf(acc[i][4 + j] + bias[bn + col], 0.f);
      }
    }
  }
}

// ============ MLP layer 2: out[n,o] = <hid[n,:], Wl2[o,:]> + bl2[o] ============
__global__ __launch_bounds__(256) void head_out(const float* __restrict__ hid,
                                                const float* __restrict__ Wl2,
                                                const float* __restrict__ bl2,
                                                float* __restrict__ out, int n_nodes) {
  int t = blockIdx.x * 256 + threadIdx.x;
  int n = t >> 4, o = t & 15;
  if (n >= n_nodes) return;
  const float4* hp = (const float4*)(hid + (size_t)n * 128);
  const float4* wp = (const float4*)(Wl2 + (size_t)o * 128);
  float acc = bl2[o];
#pragma unroll
  for (int k = 0; k < 32; ++k) {
    float4 hv = hp[k], wv = wp[k];
    acc += hv.x * wv.x + hv.y * wv.y + hv.z * wv.z + hv.w * wv.w;
  }
  out[(size_t)n * 16 + o] = acc;
}

// =========== exact (fp64) attention-score folds, both convs ===========
__global__ __launch_bounds__(256) void fold_att1(const float* __restrict__ W1,
                                                 const float* __restrict__ att_s,
                                                 const float* __restrict__ att_d,
                                                 double* __restrict__ wt) {
  int t = blockIdx.x * 256 + threadIdx.x;   // t = h*HC + k, total 1024
  if (t >= H_ * HC) return;
  int h = t >> 8;
  int k = t & (HC - 1);
  double s = 0.0, d = 0.0;
#pragma unroll 4
  for (int c = 0; c < C_; ++c) {
    double w = (double)W1[(size_t)(h * C_ + c) * HC + k];
    s += w * (double)att_s[h * C_ + c];
    d += w * (double)att_d[h * C_ + c];
  }
  wt[(size_t)(2 * h + 0) * HC + k] = s;
  wt[(size_t)(2 * h + 1) * HC + k] = d;
}

__global__ __launch_bounds__(256) void fold_att2(const float* __restrict__ W2,
                                                 const float* __restrict__ att_s,
                                                 const float* __restrict__ att_d,
                                                 double* __restrict__ u_s,
                                                 double* __restrict__ u_d) {
  int t = blockIdx.x * 256 + threadIdx.x;
  if (t >= H_ * HC) return;
  int h = t >> 8;
  int k = t & (HC - 1);
  double s = 0.0, d = 0.0;
#pragma unroll 4
  for (int c = 0; c < C_; ++c) {
    double w = (double)W2[(size_t)(h * C_ + c) * HC + k];
    s += w * (double)att_s[h * C_ + c];
    d += w * (double)att_d[h * C_ + c];
  }
  u_s[t] = s;
  u_d[t] = d;
}

// vv -> wt rows 8..39, plus cst[8] (cst[0..3]=s, cst[4..7]=d)
__global__ __launch_bounds__(256) void fold_vv(const float* __restrict__ W1,
                                               const double* __restrict__ u2s,
                                               const double* __restrict__ u2d,
                                               const float* __restrict__ b1,
                                               double* __restrict__ wt,
                                               double* __restrict__ cst) {
  int t = blockIdx.x * 256 + threadIdx.x;
  if (t < 8192) {
    int type = t >> 12;          // 0=s, 1=d
    int rem = t & 4095;          // hh*256 + j
    int j = rem & 255;
    int hh = rem >> 8;           // h*4 + h'
    int h = hh >> 2, hp = hh & 3;
    const double* u2 = type ? u2d : u2s;
    double acc = 0.0;
#pragma unroll 4
    for (int c = 0; c < C_; ++c)
      acc += (double)W1[(size_t)(h * C_ + c) * HC + j] * u2[hp * HC + h * C_ + c];
    wt[(size_t)(8 + type * 16 + hh) * HC + j] = acc;
  } else if (t < 8200) {
    int q = t - 8192;            // 0..7
    const double* u2 = (q >> 2) ? u2d : u2s;
    int hp = q & 3;
    double acc = 0.0;
    for (int k = 0; k < HC; ++k) acc += (double)b1[k] * u2[hp * HC + k];
    cst[q] = acc;
  }
}

// ====== score GEMM — C[N,40] = x[N,256] . wt[40,256]^T, fp64 acc ======
#define SNB 128
#define SKB 32
__global__ __launch_bounds__(256) void scores_gemm(const float* __restrict__ x,
                                                   const double* __restrict__ wt,
                                                   double* __restrict__ as1,
                                                   double* __restrict__ ad1,
                                                   double* __restrict__ zz, int n_nodes) {
  __shared__ float  Xs[SNB][SKB + 1];
  __shared__ double Ws[40][SKB + 1];
  const int tid = threadIdx.x;
  const int n0 = blockIdx.x * SNB;
  const int g = tid & 3;
  const int p = tid >> 2;
  double acc0[10] = {}, acc1[10] = {};
  for (int k0 = 0; k0 < HC; k0 += SKB) {
    __syncthreads();
    {
      int row = tid >> 1;
      int colb = (tid & 1) * 16;
      float* d = &Xs[row][colb];
      int n = n0 + row;
      if (n < n_nodes) {
        const float* xp = x + (size_t)n * HC + k0 + colb;
        float4 v0 = *(const float4*)(xp);
        float4 v1 = *(const float4*)(xp + 4);
        float4 v2 = *(const float4*)(xp + 8);
        float4 v3 = *(const float4*)(xp + 12);
        d[0] = v0.x;  d[1] = v0.y;  d[2] = v0.z;  d[3] = v0.w;
        d[4] = v1.x;  d[5] = v1.y;  d[6] = v1.z;  d[7] = v1.w;
        d[8] = v2.x;  d[9] = v2.y;  d[10] = v2.z; d[11] = v2.w;
        d[12] = v3.x; d[13] = v3.y; d[14] = v3.z; d[15] = v3.w;
      } else {
#pragma unroll
        for (int j = 0; j < 16; ++j) d[j] = 0.f;
      }
    }
#pragma unroll
    for (int q = 0; q < 5; ++q) {
      int idx = tid + q * 256;
      int row = idx >> 5, col = idx & 31;
      Ws[row][col] = wt[(size_t)row * HC + k0 + col];
    }
    __syncthreads();
#pragma unroll
    for (int kk = 0; kk < SKB; ++kk) {
      double xv0 = (double)Xs[2 * p][kk];
      double xv1 = (double)Xs[2 * p + 1][kk];
#pragma unroll
      for (int ci = 0; ci < 10; ++ci) {
        double w = Ws[g * 10 + ci][kk];
        acc0[ci] += xv0 * w;
        acc1[ci] += xv1 * w;
      }
    }
  }
  const int na = n0 + 2 * p;
  const int nb = na + 1;
  if (na < n_nodes) {
#pragma unroll
    for (int ci = 0; ci < 10; ++ci) {
      int c = g * 10 + ci;
      double v = acc0[ci];
      if (c < 8)       ((c & 1) ? ad1 : as1)[na * H_ + (c >> 1)] = v;
      else if (c < 24) { int hh = c - 8;  zz[((size_t)na * H_ + (hh >> 2)) * 8 + (hh & 3)] = v; }
      else             { int hh = c - 24; zz[((size_t)na * H_ + (hh >> 2)) * 8 + 4 + (hh & 3)] = v; }
    }
  }
  if (nb < n_nodes) {
#pragma unroll
    for (int ci = 0; ci < 10; ++ci) {
      int c = g * 10 + ci;
      double v = acc1[ci];
      if (c < 8)       ((c & 1) ? ad1 : as1)[nb * H_ + (c >> 1)] = v;
      else if (c < 24) { int hh = c - 8;  zz[((size_t)nb * H_ + (hh >> 2)) * 8 + (hh & 3)] = v; }
      else             { int hh = c - 24; zz[((size_t)nb * H_ + (hh >> 2)) * 8 + 4 + (hh & 3)] = v; }
    }
  }
}

// ====================== CSR build: multi-block scan ======================
__global__ void count_edges(const int* __restrict__ dst, int E_, int* __restrict__ counts) {
  int e = blockIdx.x * blockDim.x + threadIdx.x;
  if (e < E_) atomicAdd(&counts[dst[e]], 1);
}

#define SCB 256
__global__ __launch_bounds__(SCB) void scan_phase1(const int* __restrict__ counts, int n,
                                                   int* __restrict__ row_start,
                                                   int* __restrict__ bsum) {
  __shared__ int sh[SCB];
  int b = blockIdx.x, t = threadIdx.x;
  int idx = b * SCB + t;
  int v = (idx < n) ? counts[idx] : 0;
  sh[t] = v;
  __syncthreads();
  for (int off = 1; off < SCB; off <<= 1) {
    int u = (t >= off) ? sh[t - off] : 0;
    __syncthreads();
    sh[t] += u;
    __syncthreads();
  }
  if (idx < n) row_start[idx] = sh[t] - v;   // block-local exclusive
  if (t == SCB - 1) bsum[b] = sh[t];
}

__global__ __launch_bounds__(SCB) void scan_phase2(int* __restrict__ bsum, int nb) {
  __shared__ int sh[SCB];
  int t = threadIdx.x;
  int v = (t < nb) ? bsum[t] : 0;
  sh[t] = v;
  __syncthreads();
  for (int off = 1; off < SCB; off <<= 1) {
    int u = (t >= off) ? sh[t - off] : 0;
    __syncthreads();
    sh[t] += u;
    __syncthreads();
  }
  if (t < nb) bsum[t] = sh[t] - v;           // exclusive, in place
}

__global__ __launch_bounds__(SCB) void scan_phase3(int n, const int* __restrict__ bsum,
                                                   int* __restrict__ row_start,
                                                   int* __restrict__ wptr, int E_) {
  int b = blockIdx.x, t = threadIdx.x;
  int idx = b * SCB + t;
  if (idx < n) {
    int r = row_start[idx] + bsum[b];
    row_start[idx] = r;
    wptr[idx] = r;
  } else if (idx == n) {
    row_start[n] = E_;
  }
}

__global__ void scatter_edges(const int* __restrict__ src, const int* __restrict__ dst, int E_,
                              int* __restrict__ wptr, int* __restrict__ csr_src) {
  int e = blockIdx.x * blockDim.x + threadIdx.x;
  if (e < E_) {
    int p = atomicAdd(&wptr[dst[e]], 1);
    csr_src[p] = src[e];
  }
}

// only rare big nodes (deg>32) take an atomic
__global__ void bin_big(const int* __restrict__ row_start, int n_nodes,
                        int* __restrict__ list64, int* __restrict__ cnt) {
  int n = blockIdx.x * blockDim.x + threadIdx.x;
  if (n >= n_nodes) return;
  int deg = row_start[n + 1] - row_start[n];
  if (deg > 32) { int p = atomicAdd(&cnt[1], 1); list64[p] = n; }
}

// ====================== top-K select (u64-key bitonic) ======================
__device__ inline unsigned long long shfl_xor_u64(unsigned long long x, int m) {
  int lo = __shfl_xor((int)(x & 0xffffffffull), m);
  int hi = __shfl_xor((int)(x >> 32), m);
  return ((unsigned long long)(unsigned int)hi << 32) | (unsigned int)lo;
}
__device__ inline unsigned long long mono_key(double v) {
  unsigned long long u = (unsigned long long)__double_as_longlong(v);
  return (u & 0x8000000000000000ull) ? ~u : (u | 0x8000000000000000ull);
}
__device__ inline double mono_val(unsigned long long k) {
  unsigned long long u = (k & 0x8000000000000000ull) ? (k ^ 0x8000000000000000ull) : ~k;
  return __longlong_as_double((long long)u);
}

// iterates node ids directly; skips deg>32 (handled by select64)
__global__ __launch_bounds__(256) void select32(const double* __restrict__ as_,
                                                const double* __restrict__ ad_,
                                                const int* __restrict__ row_start,
                                                const int* __restrict__ csr_src,
                                                int n_nodes,
                                                int* __restrict__ ksrc,
                                                float* __restrict__ kw,
                                                double* __restrict__ kw64) {
  const int slot = threadIdx.x & 31;           // position within 32-group
  const int grp  = threadIdx.x >> 5;           // 0..7
  const int nl   = grp >> 2;                   // node-local 0..1
  const int h    = grp & 3;
  const int lane = threadIdx.x & 63;           // absolute lane in wave
  const int gbase = lane & 32;                 // group base within wave
  for (int base = blockIdx.x * 2; base < n_nodes; base += gridDim.x * 2) {
    int n = base + nl;
    bool active = (n < n_nodes);
    int nn = active ? n : 0;
    int rs = row_start[nn];
    int deg = active ? (row_start[nn + 1] - rs) : 0;
    if (deg > 32) { active = false; deg = 0; }   // big nodes -> select64
    double adv = ad_[nn * H_ + h];
    int kcount = deg < KTOP ? deg : KTOP;

    unsigned long long key; int sv;
    if (slot < deg) {
      int s = csr_src[rs + slot];
      double a = as_[s * H_ + h] + adv;
      double v = (a >= 0.0) ? a : (double)NEG_SLOPE * a;
      key = (mono_key(v) & ~31ull) | (unsigned long long)(31 - slot);
      sv = s;
    } else {
      key = (mono_key(-INFINITY) & ~31ull) | (unsigned long long)(31 - slot);
      sv = -1;
    }
#pragma unroll
    for (int kk = 2; kk <= 32; kk <<= 1) {
#pragma unroll
      for (int j = kk >> 1; j > 0; j >>= 1) {
        unsigned long long ok = shfl_xor_u64(key, j);
        bool dirDesc = ((slot & kk) == 0);
        bool lower   = ((slot & j) == 0);
        bool mineFirst = key > ok;
        if ((dirDesc == lower) ? !mineFirst : mineFirst) key = ok;
      }
    }
    int wslot = 31 - (int)(key & 31ull);
    int sid = __shfl(sv, gbase + wslot);
    double vrec = mono_val(key & ~31ull);
    double m = __shfl(vrec, gbase);            // slot 0 of group = max
    double ex = (slot < kcount) ? exp(vrec - m) : 0.0;
    double den = ex;
#pragma unroll
    for (int off = 16; off >= 1; off >>= 1) den += __shfl_xor(den, off);
    double inv = (kcount > 0) ? 1.0 / den : 0.0;
    double wgt = ex * inv;                     // exactly 0.0 beyond kcount

    if (active && slot < KTOP) {
      size_t u = ((size_t)n * H_ + h) * KTOP + slot;
      ksrc[u] = (sid >= 0) ? sid : 0;
      kw[u] = (float)wgt;
      if (kw64) kw64[u] = wgt;
    }
  }
}

__global__ __launch_bounds__(256) void select64(const double* __restrict__ as_,
                                                const double* __restrict__ ad_,
                                                const int* __restrict__ row_start,
                                                const int* __restrict__ csr_src,
                                                const int* __restrict__ list,
                                                const int* __restrict__ cnt,
                                                int* __restrict__ ksrc,
                                                float* __restrict__ kw,
                                                double* __restrict__ kw64) {
  __shared__ int    f_src[H_][16];
  __shared__ double f_w[H_][16];
  const int c = cnt[1];
  int h = threadIdx.x >> 6;
  int lane = threadIdx.x & 63;
  for (int idx = blockIdx.x; idx < c; idx += gridDim.x) {
    int n = list[idx];
    int rs = row_start[n];
    int deg = row_start[n + 1] - rs;
    if (deg > 256) deg = 256;   // safety clamp
    double adv = ad_[n * H_ + h];
    int kcount = deg < KTOP ? deg : KTOP;

    double vsel; int sid;
    if (deg <= 64) {
      unsigned long long key; int sv;
      if (lane < deg) {
        int s = csr_src[rs + lane];
        double a = as_[s * H_ + h] + adv;
        double v = (a >= 0.0) ? a : (double)NEG_SLOPE * a;
        key = (mono_key(v) & ~63ull) | (unsigned long long)(63 - lane);
        sv = s;
      } else {
        key = (mono_key(-INFINITY) & ~63ull) | (unsigned long long)(63 - lane);
        sv = -1;
      }
#pragma unroll
      for (int kk = 2; kk <= 64; kk <<= 1) {
#pragma unroll
        for (int j = kk >> 1; j > 0; j >>= 1) {
          unsigned long long ok = shfl_xor_u64(key, j);
          bool dirDesc = ((lane & kk) == 0);
          bool lower   = ((lane & j) == 0);
          bool mineFirst = key > ok;
          if ((dirDesc == lower) ? !mineFirst : mineFirst) key = ok;
        }
      }
      int wslot = 63 - (int)(key & 63ull);
      sid = __shfl(sv, wslot);
      vsel = mono_val(key & ~63ull);
    } else {
      double av[4]; int svr[4];
#pragma unroll
      for (int q = 0; q < 4; ++q) {
        int id2 = lane + (q << 6);
        if (id2 < deg) {
          int s = csr_src[rs + id2];
          double a = as_[s * H_ + h] + adv;
          av[q] = (a >= 0.0) ? a : (double)NEG_SLOPE * a;
          svr[q] = s;
        } else {
          av[q] = -INFINITY; svr[q] = -1;
        }
      }
      for (int it = 0; it < kcount; ++it) {
        double best = av[0]; int bq = 0;
#pragma unroll
        for (int q = 1; q < 4; ++q)
          if (av[q] > best) { best = av[q]; bq = q; }
        double bv = best; int bl = lane;
#pragma unroll
        for (int off = 32; off >= 1; off >>= 1) {
          double ov = __shfl_down(bv, off);
          int    ol = __shfl_down(bl, off);
          if (ov > bv || (ov == bv && ol < bl)) { bv = ov; bl = ol; }
        }
        bl = __shfl(bl, 0);
        if (lane == bl) {
          f_src[h][it] = svr[bq];
          f_w[h][it] = best;
          av[bq] = -INFINITY;
        }
      }
      vsel = (lane < kcount) ? f_w[h][lane] : -INFINITY;
      sid  = (lane < kcount) ? f_src[h][lane] : -1;
    }

    double m = __shfl(vsel, 0);
    double ex = (lane < kcount) ? exp(vsel - m) : 0.0;
    double den = ex;
#pragma unroll
    for (int off = 32; off >= 1; off >>= 1) den += __shfl_xor(den, off);
    double inv = (kcount > 0) ? 1.0 / den : 0.0;
    double wgt = ex * inv;

    if (lane < KTOP) {
      size_t u = ((size_t)n * H_ + h) * KTOP + lane;
      ksrc[u] = (sid >= 0) ? sid : 0;
      kw[u] = (float)wgt;
      if (kw64) kw64[u] = wgt;
    }
  }
}

// ====================== conv2 scores ======================
__global__ __launch_bounds__(256) void conv2_scores(const int* __restrict__ ksrc,
                                                    const double* __restrict__ kw64,
                                                    const double* __restrict__ zz,
                                                    const double* __restrict__ cst,
                                                    double* __restrict__ as2,
                                                    double* __restrict__ ad2, int n_nodes) {
  int n = (blockIdx.x * 256 + threadIdx.x) >> 6;
  int lane = threadIdx.x & 63;
  if (n >= n_nodes) return;
  int p = lane >> 3, j = lane & 7;
  const int*    sp = ksrc + (size_t)n * H_ * KTOP;
  const double* wp = kw64 + (size_t)n * H_ * KTOP;
  double acc = 0.0;
#pragma unroll
  for (int t = 0; t < 5; ++t) {
    int q = j + t * 8;                 // 0..39
    int h = q / KTOP;
    double w = wp[q];
    int s = sp[q];
    acc += w * zz[((size_t)s * H_ + h) * 8 + p];
  }
#pragma unroll
  for (int off = 4; off >= 1; off >>= 1) acc += __shfl_xor(acc, off);
  if (j == 0) {
    double vo = acc + cst[p];
    if (p < 4) as2[n * H_ + p] = vo;
    else       ad2[n * H_ + (p - 4)] = vo;
  }
}

// ====================== gather/aggregate (one node per wave, fp16 input) ======================
// R22: gathers the fp16 xl copy (128B per (n,h) slice = one cache line);
// accumulation fp32, i-ascending, w=0 beyond kcount.
template <int CONCAT>
__global__ __launch_bounds__(256) void gather_agg(const unsigned short* __restrict__ xh,
                                                  const int* __restrict__ ksrc,
                                                  const float* __restrict__ kw,
                                                  const float* __restrict__ bias,
                                                  float* __restrict__ out, int n_nodes) {
  int n = (blockIdx.x * 256 + threadIdx.x) >> 6;   // one node per wave
  int lane = threadIdx.x & 63;
  if (n >= n_nodes) return;
  const int*   sp = ksrc + (size_t)n * H_ * KTOP;
  const float* wp = kw   + (size_t)n * H_ * KTOP;
  int ss[H_ * KTOP];
#pragma unroll
  for (int k = 0; k < H_ * KTOP; ++k) ss[k] = sp[k];
  unsigned short xv[H_ * KTOP];
#pragma unroll
  for (int h = 0; h < H_; ++h)
#pragma unroll
    for (int i = 0; i < KTOP; ++i)
      xv[h * KTOP + i] = xh[(size_t)ss[h * KTOP + i] * HC + h * C_ + lane];
  float accs[H_];
#pragma unroll
  for (int h = 0; h < H_; ++h) {
    float a = 0.f;
#pragma unroll
    for (int i = 0; i < KTOP; ++i) a += wp[h * KTOP + i] * h2f(xv[h * KTOP + i]);
    accs[h] = a;
  }
  if (CONCAT) {
#pragma unroll
    for (int h = 0; h < H_; ++h)
      out[(size_t)n * HC + h * C_ + lane] = accs[h] + bias[h * C_ + lane];
  } else {
    out[(size_t)n * C_ + lane] =
        0.25f * (accs[0] + accs[1] + accs[2] + accs[3]) + bias[lane];
  }
}

// ============================== launcher ==============================
extern "C" void kernel_launch(void* const* d_in, const int* in_sizes, int n_in,
                              void* d_out, int out_size, void* d_ws, size_t ws_size,
                              hipStream_t stream) {
  const float* x      = (const float*)d_in[0];
  const float* W1     = (const float*)d_in[1];
  const float* att_s1 = (const float*)d_in[2];
  const float* att_d1 = (const float*)d_in[3];
  const float* b1     = (const float*)d_in[4];
  const float* W2     = (const float*)d_in[5];
  const float* att_s2 = (const float*)d_in[6];
  const float* att_d2 = (const float*)d_in[7];
  const float* b2     = (const float*)d_in[8];
  const float* Wl1    = (const float*)d_in[9];
  const float* bl1    = (const float*)d_in[10];
  const float* Wl2    = (const float*)d_in[11];
  const float* bl2    = (const float*)d_in[12];
  const int*   eidx   = (const int*)d_in[13];

  const int N_ = in_sizes[0] / F_IN;     // 50000
  const int E_ = in_sizes[13] / 2;       // 800000
  const int* e_src = eidx;
  const int* e_dst = eidx + E_;

  // workspace layout
  char* base = (char*)d_ws;
  size_t off = 0;
  auto alloc = [&](size_t bytes) -> char* {
    char* p = base + off;
    off = (off + bytes + 255) & ~(size_t)255;
    return p;
  };
  float*  hid       = (float*)alloc((size_t)N_ * 128 * 4);       // MLP hidden
  unsigned short* xlh = (unsigned short*)alloc((size_t)N_ * HC * 2);  // fp16 GEMM out / gather in
  float*  hbuf      = (float*)alloc((size_t)N_ * HC * 4);        // h1; later h2 (N*64)
  double* as1       = (double*)alloc((size_t)N_ * H_ * 8);
  double* ad1       = (double*)alloc((size_t)N_ * H_ * 8);
  double* as2       = (double*)alloc((size_t)N_ * H_ * 8);
  double* ad2       = (double*)alloc((size_t)N_ * H_ * 8);
  double* zz        = (double*)alloc((size_t)N_ * H_ * 8 * 8);   // [s][h][8] packed
  double* wt        = (double*)alloc((size_t)40 * HC * 8);
  double* u2s       = (double*)alloc((size_t)H_ * HC * 8);
  double* u2d       = (double*)alloc((size_t)H_ * HC * 8);
  double* cst       = (double*)alloc((size_t)8 * 8);
  int*    ksrc1     = (int*)alloc((size_t)N_ * H_ * KTOP * 4);
  float*  kw1       = (float*)alloc((size_t)N_ * H_ * KTOP * 4);
  double* kw64_1    = (double*)alloc((size_t)N_ * H_ * KTOP * 8);
  int*    ksrc2     = (int*)alloc((size_t)N_ * H_ * KTOP * 4);
  float*  kw2       = (float*)alloc((size_t)N_ * H_ * KTOP * 4);
  int*    list64    = (int*)alloc((size_t)N_ * 4);
  int*    cnt       = (int*)alloc((size_t)8 * 4);
  int*    bsum      = (int*)alloc((size_t)SCB * 4);
  int* counts       = (int*)alloc((size_t)N_ * 4);
  int* row_start    = (int*)alloc((size_t)(N_ + 1) * 4);
  int* wptr         = (int*)alloc((size_t)N_ * 4);
  int* csr_src      = (int*)alloc((size_t)E_ * 4);
  (void)ws_size;

  const int eb = (E_ + 255) / 256;
  const int nb = (N_ + 255) / 256;
  const int sb = (N_ + 1 + SCB - 1) / SCB;

  // ---- CSR build (multi-block scan) + big-node list ----
  hipMemsetAsync(counts, 0, (size_t)N_ * 4, stream);
  hipMemsetAsync(cnt, 0, 32, stream);
  count_edges<<<eb, 256, 0, stream>>>(e_dst, E_, counts);
  scan_phase1<<<sb, SCB, 0, stream>>>(counts, N_, row_start, bsum);
  scan_phase2<<<1, SCB, 0, stream>>>(bsum, sb);
  scan_phase3<<<sb, SCB, 0, stream>>>(N_, bsum, row_start, wptr, E_);
  scatter_edges<<<eb, 256, 0, stream>>>(e_src, e_dst, E_, wptr, csr_src);
  bin_big<<<nb, 256, 0, stream>>>(row_start, N_, list64, cnt);

  // ---- fp64 score folds + score GEMM ----
  fold_att1<<<(H_ * HC + 255) / 256, 256, 0, stream>>>(W1, att_s1, att_d1, wt);
  fold_att2<<<(H_ * HC + 255) / 256, 256, 0, stream>>>(W2, att_s2, att_d2, u2s, u2d);
  fold_vv<<<(8200 + 255) / 256, 256, 0, stream>>>(W1, u2s, u2d, b1, wt, cst);
  scores_gemm<<<(N_ + SNB - 1) / SNB, 256, 0, stream>>>(x, wt, as1, ad1, zz, N_);

  // ---- conv1 value GEMM (bf16x3 MFMA -> fp16 out) ----
  dim3 ggrid((N_ + GM - 1) / GM, HC / GN);
  gemm_nt_mfma<<<ggrid, 256, 0, stream>>>(x, W1, xlh, N_, F_IN, HC);

  // ---- selection conv1 (binned) + exact conv2 scores ----
  select32<<<6250, 256, 0, stream>>>(as1, ad1, row_start, csr_src, N_, ksrc1, kw1, kw64_1);
  select64<<<1024, 256, 0, stream>>>(as1, ad1, row_start, csr_src, list64, cnt,
                                     ksrc1, kw1, kw64_1);
  conv2_scores<<<(N_ + 3) / 4, 256, 0, stream>>>(ksrc1, kw64_1, zz, cst, as2, ad2, N_);

  // ---- selection conv2 (binned) ----
  select32<<<6250, 256, 0, stream>>>(as2, ad2, row_start, csr_src, N_, ksrc2, kw2, nullptr);
  select64<<<1024, 256, 0, stream>>>(as2, ad2, row_start, csr_src, list64, cnt,
                                     ksrc2, kw2, nullptr);

  const int agg_blocks = (N_ + 3) / 4;   // one node per 64-lane wave

  // ---- conv1 aggregate ----
  gather_agg<1><<<agg_blocks, 256, 0, stream>>>(xlh, ksrc1, kw1, b1, hbuf, N_);

  // ---- conv2 ----
  gemm_nt_mfma<<<ggrid, 256, 0, stream>>>(hbuf, W2, xlh, N_, HC, HC);
  gather_agg<0><<<agg_blocks, 256, 0, stream>>>(xlh, ksrc2, kw2, b2, hbuf, N_);

  // ---- MLP head ----
  dim3 hgrid((N_ + BM - 1) / BM, 1);
  gemm_bias_relu<<<hgrid, 256, 0, stream>>>(hbuf, Wl1, bl1, hid, N_, C_, 128);
  head_out<<<(N_ * 16 + 255) / 256, 256, 0, stream>>>(hid, Wl2, bl2, (float*)d_out, N_);
}